// Round 4
// baseline (506.642 us; speedup 1.0000x reference)
//
#include <hip/hip_runtime.h>

// ---- problem constants ----
#define L_SEQ   2048
#define DMODEL  1024
#define DINNER  2048
#define DSTATE  16
#define RANK    64
#define NPROJ   96      // RANK + 2*DSTATE
#define XZDIM   4096    // 2*DINNER
#define CHUNK   32
#define NCHUNK  64      // CHUNK*NCHUNK == L_SEQ

typedef __bf16 bf16x8 __attribute__((ext_vector_type(8)));
typedef float  f32x4  __attribute__((ext_vector_type(4)));

__device__ __forceinline__ unsigned short f2bf(float f) {
  unsigned int x = __float_as_uint(f);
  x += 0x7FFF + ((x >> 16) & 1);          // round-to-nearest-even
  return (unsigned short)(x >> 16);
}

#define GLD16(g, l)                                                            \
  __builtin_amdgcn_global_load_lds(                                            \
      (const __attribute__((address_space(1))) void*)(g),                      \
      (__attribute__((address_space(3))) void*)(l), 16, 0, 0)

// ============================================================
// f32 -> bf16 convert, 8 elems/thread, exact grid (n % 2048 == 0)
// ============================================================
__global__ __launch_bounds__(256) void f32_to_bf16_kernel(
    const float* __restrict__ src, unsigned short* __restrict__ dst) {
  size_t i = ((size_t)blockIdx.x * 256 + threadIdx.x) * 8;
  float4 v0 = *(const float4*)(src + i);
  float4 v1 = *(const float4*)(src + i + 4);
  unsigned short o[8];
  o[0] = f2bf(v0.x); o[1] = f2bf(v0.y); o[2] = f2bf(v0.z); o[3] = f2bf(v0.w);
  o[4] = f2bf(v1.x); o[5] = f2bf(v1.y); o[6] = f2bf(v1.z); o[7] = f2bf(v1.w);
  *(ushort4*)(dst + i)     = make_ushort4(o[0], o[1], o[2], o[3]);
  *(ushort4*)(dst + i + 4) = make_ushort4(o[4], o[5], o[6], o[7]);
}

// ============================================================
// bf16 MFMA GEMM (m97 structure):  C[M][N] = A[M][K] * B[N][K]^T
// A,B bf16 K-contiguous; C f32. 128x128 tile, BK=32, 256 thr (4 waves),
// each wave 64x64 via 4x4 frags of mfma_f32_16x16x32_bf16.
// LDS linear (global_load_lds width=16), 2-barrier K-loop.
// ============================================================
__global__ __launch_bounds__(256) void gemm_nt_bf16(
    const unsigned short* __restrict__ A, const unsigned short* __restrict__ B,
    float* __restrict__ C, int M, int N, int K) {
  __shared__ unsigned short As[128 * 32];
  __shared__ unsigned short Bs[128 * 32];
  const int tid  = threadIdx.x;
  const int lane = tid & 63;
  const int wave = tid >> 6;
  const int wr = wave >> 1, wc = wave & 1;
  const int fr = lane & 15;          // fragment row (A) / col (B) index
  const int kq = (lane >> 4) * 8;    // per-lane k sub-offset
  const size_t bm = blockIdx.y, bn = blockIdx.x;

  f32x4 acc[4][4] = {};

  const int q0 = tid, q1 = tid + 256;          // 16B-chunk ids (512 total)
  const unsigned short* a0 = A + (bm * 128 + (q0 >> 2)) * (size_t)K + (q0 & 3) * 8;
  const unsigned short* a1 = A + (bm * 128 + (q1 >> 2)) * (size_t)K + (q1 & 3) * 8;
  const unsigned short* b0 = B + (bn * 128 + (q0 >> 2)) * (size_t)K + (q0 & 3) * 8;
  const unsigned short* b1 = B + (bn * 128 + (q1 >> 2)) * (size_t)K + (q1 & 3) * 8;

  for (int k0 = 0; k0 < K; k0 += 32) {
    GLD16(a0 + k0, &As[q0 * 8]);
    GLD16(a1 + k0, &As[q1 * 8]);
    GLD16(b0 + k0, &Bs[q0 * 8]);
    GLD16(b1 + k0, &Bs[q1 * 8]);
    __syncthreads();                 // drains vmcnt before LDS reads
    bf16x8 af[4], bg[4];
#pragma unroll
    for (int m = 0; m < 4; m++)
      af[m] = *(const bf16x8*)&As[(wr * 64 + m * 16 + fr) * 32 + kq];
#pragma unroll
    for (int n = 0; n < 4; n++)
      bg[n] = *(const bf16x8*)&Bs[(wc * 64 + n * 16 + fr) * 32 + kq];
#pragma unroll
    for (int m = 0; m < 4; m++)
#pragma unroll
      for (int n = 0; n < 4; n++)
        acc[m][n] = __builtin_amdgcn_mfma_f32_16x16x32_bf16(af[m], bg[n],
                                                            acc[m][n], 0, 0, 0);
    __syncthreads();                 // protect LDS before next stage
  }
  const int cr = (lane >> 4) * 4;    // C/D: col=lane&15, row=(lane>>4)*4+reg
#pragma unroll
  for (int m = 0; m < 4; m++)
#pragma unroll
    for (int n = 0; n < 4; n++) {
      float* cp = C + (bm * 128 + wr * 64 + m * 16 + cr) * (size_t)N +
                  bn * 128 + wc * 64 + n * 16 + fr;
#pragma unroll
      for (int r = 0; r < 4; r++) cp[(size_t)r * N] = acc[m][n][r];
    }
}

// ============================================================
// Depthwise causal conv (k=4) + bias + SiLU.
// ============================================================
__global__ void conv_silu_kernel(const float* __restrict__ xz,
                                 const float* __restrict__ w,
                                 const float* __restrict__ b,
                                 float* __restrict__ xconv) {
  int idx = blockIdx.x * 256 + threadIdx.x;      // l*DINNER + d
  int d = idx & (DINNER - 1);
  int l = idx >> 11;
  float4 wv = *(const float4*)(w + (size_t)d * 4);
  float wa[4] = {wv.x, wv.y, wv.z, wv.w};
  float acc = b[d];
#pragma unroll
  for (int t = 0; t < 4; t++) {
    int ll = l - 3 + t;
    if (ll >= 0) acc += xz[(size_t)ll * XZDIM + d] * wa[t];
  }
  float s = acc / (1.0f + __expf(-acc));
  xconv[idx] = s;
}

// ============================================================
// x_dbl[l][j] = sum_d xconv[l][d] * x_proj_w[j][d]   (j in [0,96))
// ============================================================
__global__ __launch_bounds__(256) void xdbl_kernel(
    const float* __restrict__ xconv, const float* __restrict__ xw,
    float* __restrict__ xdbl) {
  __shared__ float xs[8][256];
  int l0 = blockIdx.x * 8;
  int tid = threadIdx.x;
  float acc[3] = {0.f, 0.f, 0.f};
  for (int kc = 0; kc < DINNER; kc += 256) {
    __syncthreads();
#pragma unroll
    for (int i = 0; i < 8; i++)
      xs[i][tid] = xconv[(size_t)(l0 + i) * DINNER + kc + tid];
    __syncthreads();
#pragma unroll
    for (int t = 0; t < 3; t++) {
      int o = tid + t * 256;
      int r = o / 96, j = o - r * 96;
      const float4* wr4 = (const float4*)(xw + (size_t)j * DINNER + kc);
      float a = acc[t];
#pragma unroll 8
      for (int k4 = 0; k4 < 64; k4++) {
        float4 w4 = wr4[k4];
        a += xs[r][k4 * 4 + 0] * w4.x + xs[r][k4 * 4 + 1] * w4.y +
             xs[r][k4 * 4 + 2] * w4.z + xs[r][k4 * 4 + 3] * w4.w;
      }
      acc[t] = a;
    }
  }
#pragma unroll
  for (int t = 0; t < 3; t++) {
    int o = tid + t * 256;
    int r = o / 96, j = o - r * 96;
    xdbl[(size_t)(l0 + r) * NPROJ + j] = acc[t];
  }
}

// ============================================================
// dt[l][d] = softplus( dt_lr @ dt_proj_w.T + b )
// 8 rows per block: dt_proj_w float4s amortized over 8 accumulators
// (cuts weight re-reads 8x vs one-row-per-block).
// ============================================================
__global__ __launch_bounds__(256) void dt_kernel(
    const float* __restrict__ xdbl, const float* __restrict__ dtw,
    const float* __restrict__ dtb, float* __restrict__ dt) {
  __shared__ float rl[8][RANK];
  int l0 = blockIdx.x * 8;
  int tid = threadIdx.x;
  for (int i = tid; i < 8 * RANK; i += 256) {
    int r = i >> 6, j = i & 63;
    rl[r][j] = xdbl[(size_t)(l0 + r) * NPROJ + j];
  }
  __syncthreads();
  for (int d = tid; d < DINNER; d += 256) {
    float bias = dtb[d];
    float accv[8];
#pragma unroll
    for (int r = 0; r < 8; r++) accv[r] = bias;
    const float4* wr = (const float4*)(dtw + (size_t)d * RANK);
#pragma unroll
    for (int k4 = 0; k4 < 16; k4++) {
      float4 w4 = wr[k4];
#pragma unroll
      for (int r = 0; r < 8; r++)
        accv[r] += rl[r][k4 * 4 + 0] * w4.x + rl[r][k4 * 4 + 1] * w4.y +
                   rl[r][k4 * 4 + 2] * w4.z + rl[r][k4 * 4 + 3] * w4.w;
    }
#pragma unroll
    for (int r = 0; r < 8; r++) {
      float a = accv[r];
      float sp = (a > 20.f) ? a : log1pf(__expf(a));
      dt[(size_t)(l0 + r) * DINNER + d] = sp;
    }
  }
}

// ============================================================
// Scan phase A: per (chunk, channel) local scan, h0 = 0.
// ============================================================
__global__ __launch_bounds__(256) void scan_a_kernel(
    const float* __restrict__ dt, const float* __restrict__ xconv,
    const float* __restrict__ xdbl, const float* __restrict__ A_log,
    float* __restrict__ Pout, float* __restrict__ Hout) {
  __shared__ float Bsm[CHUNK][DSTATE];
  int c = blockIdx.x;
  int d = blockIdx.y * 256 + threadIdx.x;
  for (int i = threadIdx.x; i < CHUNK * DSTATE; i += 256) {
    int l = i >> 4, n = i & 15;
    Bsm[l][n] = xdbl[(size_t)(c * CHUNK + l) * NPROJ + RANK + n];
  }
  __syncthreads();
  float a[16], h[16], P[16];
  const float4* al4 = (const float4*)(A_log + (size_t)d * 16);
#pragma unroll
  for (int q = 0; q < 4; q++) {
    float4 v = al4[q];
    a[q * 4 + 0] = -__expf(v.x); a[q * 4 + 1] = -__expf(v.y);
    a[q * 4 + 2] = -__expf(v.z); a[q * 4 + 3] = -__expf(v.w);
  }
#pragma unroll
  for (int n = 0; n < 16; n++) { h[n] = 0.f; P[n] = 1.f; }
  for (int l = 0; l < CHUNK; l++) {
    int gl = c * CHUNK + l;
    float dtv = dt[(size_t)gl * DINNER + d];
    float xv = xconv[(size_t)gl * DINNER + d];
    float dtx = dtv * xv;
#pragma unroll
    for (int n = 0; n < 16; n++) {
      float dA = __expf(dtv * a[n]);
      P[n] *= dA;
      h[n] = dA * h[n] + dtx * Bsm[l][n];
    }
  }
#pragma unroll
  for (int n = 0; n < 16; n++) {
    size_t o = ((size_t)c * 16 + n) * DINNER + d;
    Pout[o] = P[n];
    Hout[o] = h[n];
  }
}

// ============================================================
// Combine: sequential scan over the NCHUNK chunk boundaries.
// ============================================================
__global__ void combine_kernel(const float* __restrict__ P,
                               const float* __restrict__ Hl,
                               float* __restrict__ H0) {
  int i = blockIdx.x * 256 + threadIdx.x;  // n*DINNER + d
  float h = 0.f;
  for (int c = 0; c < NCHUNK; c++) {
    size_t o = (size_t)c * (DINNER * DSTATE) + i;
    H0[o] = h;
    h = P[o] * h + Hl[o];
  }
}

// ============================================================
// Scan phase C: replay with correct h0, fuse y + D*x + silu(z) gate,
// emit yz directly as bf16 for the out-GEMM.
// ============================================================
__global__ __launch_bounds__(256) void scan_c_kernel(
    const float* __restrict__ dt, const float* __restrict__ xconv,
    const float* __restrict__ xdbl, const float* __restrict__ A_log,
    const float* __restrict__ H0, const float* __restrict__ xz,
    const float* __restrict__ Dp, unsigned short* __restrict__ yzbf) {
  __shared__ float Bsm[CHUNK][DSTATE];
  __shared__ float Csm[CHUNK][DSTATE];
  int c = blockIdx.x;
  int d = blockIdx.y * 256 + threadIdx.x;
  for (int i = threadIdx.x; i < CHUNK * DSTATE; i += 256) {
    int l = i >> 4, n = i & 15;
    size_t base = (size_t)(c * CHUNK + l) * NPROJ + RANK;
    Bsm[l][n] = xdbl[base + n];
    Csm[l][n] = xdbl[base + DSTATE + n];
  }
  __syncthreads();
  float a[16], h[16];
  const float4* al4 = (const float4*)(A_log + (size_t)d * 16);
#pragma unroll
  for (int q = 0; q < 4; q++) {
    float4 v = al4[q];
    a[q * 4 + 0] = -__expf(v.x); a[q * 4 + 1] = -__expf(v.y);
    a[q * 4 + 2] = -__expf(v.z); a[q * 4 + 3] = -__expf(v.w);
  }
#pragma unroll
  for (int n = 0; n < 16; n++)
    h[n] = H0[(size_t)c * (DINNER * DSTATE) + n * DINNER + d];
  float dp = Dp[d];
  for (int l = 0; l < CHUNK; l++) {
    int gl = c * CHUNK + l;
    float dtv = dt[(size_t)gl * DINNER + d];
    float xv = xconv[(size_t)gl * DINNER + d];
    float dtx = dtv * xv;
    float y = 0.f;
#pragma unroll
    for (int n = 0; n < 16; n++) {
      float dA = __expf(dtv * a[n]);
      h[n] = dA * h[n] + dtx * Bsm[l][n];
      y += h[n] * Csm[l][n];
    }
    y += xv * dp;
    float zv = xz[(size_t)gl * XZDIM + DINNER + d];
    float sz = zv / (1.0f + __expf(-zv));
    yzbf[(size_t)gl * DINNER + d] = f2bf(y * sz);
  }
}

// ============================================================
extern "C" void kernel_launch(void* const* d_in, const int* in_sizes, int n_in,
                              void* d_out, int out_size, void* d_ws, size_t ws_size,
                              hipStream_t stream) {
  const float* x          = (const float*)d_in[0];
  const float* in_proj_w  = (const float*)d_in[1];
  const float* conv_w     = (const float*)d_in[2];
  const float* conv_b     = (const float*)d_in[3];
  const float* x_proj_w   = (const float*)d_in[4];
  const float* dt_proj_w  = (const float*)d_in[5];
  const float* dt_proj_b  = (const float*)d_in[6];
  const float* A_log      = (const float*)d_in[7];
  const float* D_param    = (const float*)d_in[8];
  const float* out_proj_w = (const float*)d_in[9];
  float* out = (float*)d_out;

  float* ws = (float*)d_ws;
  float* xz    = ws;                                   // 8,388,608 f
  float* xconv = xz    + (size_t)L_SEQ * XZDIM;        // 4,194,304 f
  float* xdbl  = xconv + (size_t)L_SEQ * DINNER;       //   196,608 f
  float* dt    = xdbl  + (size_t)L_SEQ * NPROJ;        // 4,194,304 f
  float* P     = dt    + (size_t)L_SEQ * DINNER;       // 2,097,152 f
  float* Hl    = P     + (size_t)NCHUNK * DINNER * DSTATE;
  float* H0    = Hl    + (size_t)NCHUNK * DINNER * DSTATE;
  unsigned short* bf = (unsigned short*)(H0 + (size_t)NCHUNK * DINNER * DSTATE);
  unsigned short* x_bf    = bf;                               // 2,097,152 e
  unsigned short* win_bf  = x_bf    + (size_t)L_SEQ * DMODEL;  // 4,194,304 e
  unsigned short* wout_bf = win_bf  + (size_t)XZDIM * DMODEL;  // 2,097,152 e
  unsigned short* yz_bf   = wout_bf + (size_t)DMODEL * DINNER; // 4,194,304 e

  // 0. f32 -> bf16 converts for MFMA operands
  f32_to_bf16_kernel<<<(L_SEQ * DMODEL) / 2048, 256, 0, stream>>>(x, x_bf);
  f32_to_bf16_kernel<<<(XZDIM * DMODEL) / 2048, 256, 0, stream>>>(in_proj_w, win_bf);
  f32_to_bf16_kernel<<<(DMODEL * DINNER) / 2048, 256, 0, stream>>>(out_proj_w, wout_bf);

  // 1. xz = x @ in_proj_w.T            (2048 x 4096, K=1024)
  gemm_nt_bf16<<<dim3(XZDIM / 128, L_SEQ / 128), 256, 0, stream>>>(
      x_bf, win_bf, xz, L_SEQ, XZDIM, DMODEL);
  // 2. depthwise conv + SiLU
  conv_silu_kernel<<<(L_SEQ * DINNER) / 256, 256, 0, stream>>>(
      xz, conv_w, conv_b, xconv);
  // 3. x_dbl = xconv @ x_proj_w.T      (2048 x 96)
  xdbl_kernel<<<L_SEQ / 8, 256, 0, stream>>>(xconv, x_proj_w, xdbl);
  // 4. dt = softplus(dt_lr @ dt_proj_w.T + b)
  dt_kernel<<<L_SEQ / 8, 256, 0, stream>>>(xdbl, dt_proj_w, dt_proj_b, dt);
  // 5. scan phase A
  scan_a_kernel<<<dim3(NCHUNK, DINNER / 256), 256, 0, stream>>>(
      dt, xconv, xdbl, A_log, P, Hl);
  // 6. combine chunk boundaries
  combine_kernel<<<(DINNER * DSTATE) / 256, 256, 0, stream>>>(P, Hl, H0);
  // 7. scan phase C (replay + gate, bf16 out)
  scan_c_kernel<<<dim3(NCHUNK, DINNER / 256), 256, 0, stream>>>(
      dt, xconv, xdbl, A_log, H0, xz, D_param, yz_bf);
  // 8. out = yz @ out_proj_w.T         (2048 x 1024, K=2048)
  gemm_nt_bf16<<<dim3(DMODEL / 128, L_SEQ / 128), 256, 0, stream>>>(
      yz_bf, wout_bf, out, L_SEQ, DMODEL, DINNER);
}

// Round 5
// 336.427 us; speedup vs baseline: 1.5060x; 1.5060x over previous
//
#include <hip/hip_runtime.h>

// ---- problem constants ----
#define L_SEQ   2048
#define DMODEL  1024
#define DINNER  2048
#define DSTATE  16
#define RANK    64
#define NPROJ   96      // RANK + 2*DSTATE
#define NPAD    128     // padded x_proj rows for MFMA tile
#define XZDIM   4096    // 2*DINNER
#define CHUNK   32
#define NCHUNK  64      // CHUNK*NCHUNK == L_SEQ
#define SPLITK  8       // split-K for the x_dbl GEMM

typedef __bf16 bf16x8 __attribute__((ext_vector_type(8)));
typedef float  f32x4  __attribute__((ext_vector_type(4)));

__device__ __forceinline__ unsigned short f2bf(float f) {
  unsigned int x = __float_as_uint(f);
  x += 0x7FFF + ((x >> 16) & 1);          // round-to-nearest-even
  return (unsigned short)(x >> 16);
}

#define GLD16(g, l)                                                            \
  __builtin_amdgcn_global_load_lds(                                            \
      (const __attribute__((address_space(1))) void*)(g),                      \
      (__attribute__((address_space(3))) void*)(l), 16, 0, 0)

// ============================================================
// f32 -> bf16 convert, 8 elems/thread (n % 2048 == 0)
// ============================================================
__global__ __launch_bounds__(256) void f32_to_bf16_kernel(
    const float* __restrict__ src, unsigned short* __restrict__ dst) {
  size_t i = ((size_t)blockIdx.x * 256 + threadIdx.x) * 8;
  float4 v0 = *(const float4*)(src + i);
  float4 v1 = *(const float4*)(src + i + 4);
  unsigned short o[8];
  o[0] = f2bf(v0.x); o[1] = f2bf(v0.y); o[2] = f2bf(v0.z); o[3] = f2bf(v0.w);
  o[4] = f2bf(v1.x); o[5] = f2bf(v1.y); o[6] = f2bf(v1.z); o[7] = f2bf(v1.w);
  *(ushort4*)(dst + i)     = make_ushort4(o[0], o[1], o[2], o[3]);
  *(ushort4*)(dst + i + 4) = make_ushort4(o[4], o[5], o[6], o[7]);
}

// ============================================================
// x_proj_w (96 x 2048 f32) -> bf16 padded to 128 rows (rows 96+ = 0)
// ============================================================
__global__ __launch_bounds__(256) void pad_convert_xw_kernel(
    const float* __restrict__ src, unsigned short* __restrict__ dst) {
  size_t i = ((size_t)blockIdx.x * 256 + threadIdx.x) * 8;  // over 128*2048
  int row = (int)(i >> 11);
  unsigned short o[8];
  if (row < NPROJ) {
    float4 v0 = *(const float4*)(src + i);
    float4 v1 = *(const float4*)(src + i + 4);
    o[0] = f2bf(v0.x); o[1] = f2bf(v0.y); o[2] = f2bf(v0.z); o[3] = f2bf(v0.w);
    o[4] = f2bf(v1.x); o[5] = f2bf(v1.y); o[6] = f2bf(v1.z); o[7] = f2bf(v1.w);
  } else {
    for (int t = 0; t < 8; t++) o[t] = 0;
  }
  *(ushort4*)(dst + i)     = make_ushort4(o[0], o[1], o[2], o[3]);
  *(ushort4*)(dst + i + 4) = make_ushort4(o[4], o[5], o[6], o[7]);
}

// ============================================================
// bf16 MFMA GEMM (m97 structure):  C[M][N] = A[M][K] * B[N][K]^T
// 128x128 tile, BK=32, 256 thr (4 waves), 4x4 frags 16x16x32.
// ============================================================
__global__ __launch_bounds__(256) void gemm_nt_bf16(
    const unsigned short* __restrict__ A, const unsigned short* __restrict__ B,
    float* __restrict__ C, int M, int N, int K) {
  __shared__ unsigned short As[128 * 32];
  __shared__ unsigned short Bs[128 * 32];
  const int tid  = threadIdx.x;
  const int lane = tid & 63;
  const int wave = tid >> 6;
  const int wr = wave >> 1, wc = wave & 1;
  const int fr = lane & 15;
  const int kq = (lane >> 4) * 8;
  const size_t bm = blockIdx.y, bn = blockIdx.x;

  f32x4 acc[4][4] = {};

  const int q0 = tid, q1 = tid + 256;
  const unsigned short* a0 = A + (bm * 128 + (q0 >> 2)) * (size_t)K + (q0 & 3) * 8;
  const unsigned short* a1 = A + (bm * 128 + (q1 >> 2)) * (size_t)K + (q1 & 3) * 8;
  const unsigned short* b0 = B + (bn * 128 + (q0 >> 2)) * (size_t)K + (q0 & 3) * 8;
  const unsigned short* b1 = B + (bn * 128 + (q1 >> 2)) * (size_t)K + (q1 & 3) * 8;

  for (int k0 = 0; k0 < K; k0 += 32) {
    GLD16(a0 + k0, &As[q0 * 8]);
    GLD16(a1 + k0, &As[q1 * 8]);
    GLD16(b0 + k0, &Bs[q0 * 8]);
    GLD16(b1 + k0, &Bs[q1 * 8]);
    __syncthreads();
    bf16x8 af[4], bg[4];
#pragma unroll
    for (int m = 0; m < 4; m++)
      af[m] = *(const bf16x8*)&As[(wr * 64 + m * 16 + fr) * 32 + kq];
#pragma unroll
    for (int n = 0; n < 4; n++)
      bg[n] = *(const bf16x8*)&Bs[(wc * 64 + n * 16 + fr) * 32 + kq];
#pragma unroll
    for (int m = 0; m < 4; m++)
#pragma unroll
      for (int n = 0; n < 4; n++)
        acc[m][n] = __builtin_amdgcn_mfma_f32_16x16x32_bf16(af[m], bg[n],
                                                            acc[m][n], 0, 0, 0);
    __syncthreads();
  }
  const int cr = (lane >> 4) * 4;    // C/D: col=lane&15, row=(lane>>4)*4+reg
#pragma unroll
  for (int m = 0; m < 4; m++)
#pragma unroll
    for (int n = 0; n < 4; n++) {
      float* cp = C + (bm * 128 + wr * 64 + m * 16 + cr) * (size_t)N +
                  bn * 128 + wc * 64 + n * 16 + fr;
#pragma unroll
      for (int r = 0; r < 4; r++) cp[(size_t)r * N] = acc[m][n][r];
    }
}

// ============================================================
// Split-K GEMM for x_dbl: A = xconv_bf (2048 x 2048), B = wpad_bf
// (128 x 2048). grid (SPLITK, M/128); each split does K-range 256.
// Writes f32 partials Cp[s][2048][128].
// ============================================================
__global__ __launch_bounds__(256) void gemm_xdbl_splitk(
    const unsigned short* __restrict__ A, const unsigned short* __restrict__ B,
    float* __restrict__ Cp) {
  __shared__ unsigned short As[128 * 32];
  __shared__ unsigned short Bs[128 * 32];
  const int K = DINNER;
  const int tid  = threadIdx.x;
  const int lane = tid & 63;
  const int wave = tid >> 6;
  const int wr = wave >> 1, wc = wave & 1;
  const int fr = lane & 15;
  const int kq = (lane >> 4) * 8;
  const int s = blockIdx.x;
  const size_t bm = blockIdx.y;

  f32x4 acc[4][4] = {};

  const int q0 = tid, q1 = tid + 256;
  const unsigned short* a0 = A + (bm * 128 + (q0 >> 2)) * (size_t)K + (q0 & 3) * 8;
  const unsigned short* a1 = A + (bm * 128 + (q1 >> 2)) * (size_t)K + (q1 & 3) * 8;
  const unsigned short* b0 = B + ((size_t)(q0 >> 2)) * K + (q0 & 3) * 8;
  const unsigned short* b1 = B + ((size_t)(q1 >> 2)) * K + (q1 & 3) * 8;

  const int kbeg = s * (DINNER / SPLITK), kend = kbeg + DINNER / SPLITK;
  for (int k0 = kbeg; k0 < kend; k0 += 32) {
    GLD16(a0 + k0, &As[q0 * 8]);
    GLD16(a1 + k0, &As[q1 * 8]);
    GLD16(b0 + k0, &Bs[q0 * 8]);
    GLD16(b1 + k0, &Bs[q1 * 8]);
    __syncthreads();
    bf16x8 af[4], bg[4];
#pragma unroll
    for (int m = 0; m < 4; m++)
      af[m] = *(const bf16x8*)&As[(wr * 64 + m * 16 + fr) * 32 + kq];
#pragma unroll
    for (int n = 0; n < 4; n++)
      bg[n] = *(const bf16x8*)&Bs[(wc * 64 + n * 16 + fr) * 32 + kq];
#pragma unroll
    for (int m = 0; m < 4; m++)
#pragma unroll
      for (int n = 0; n < 4; n++)
        acc[m][n] = __builtin_amdgcn_mfma_f32_16x16x32_bf16(af[m], bg[n],
                                                            acc[m][n], 0, 0, 0);
    __syncthreads();
  }
  const int cr = (lane >> 4) * 4;
  float* Cs = Cp + (size_t)s * L_SEQ * NPAD;
#pragma unroll
  for (int m = 0; m < 4; m++)
#pragma unroll
    for (int n = 0; n < 4; n++) {
      float* cp = Cs + (bm * 128 + wr * 64 + m * 16 + cr) * (size_t)NPAD +
                  wc * 64 + n * 16 + fr;
#pragma unroll
      for (int r = 0; r < 4; r++) cp[(size_t)r * NPAD] = acc[m][n][r];
    }
}

// ============================================================
// Reduce split-K partials -> xdbl[l][96]
// ============================================================
__global__ __launch_bounds__(256) void xdbl_reduce_kernel(
    const float* __restrict__ Cp, float* __restrict__ xdbl) {
  int i = blockIdx.x * 256 + threadIdx.x;    // 0 .. L_SEQ*NPROJ-1
  int l = i / NPROJ, j = i - l * NPROJ;
  float s = 0.f;
#pragma unroll
  for (int t = 0; t < SPLITK; t++)
    s += Cp[((size_t)t * L_SEQ + l) * NPAD + j];
  xdbl[i] = s;
}

// ============================================================
// Depthwise causal conv (k=4) + bias + SiLU. f32 + bf16 outputs.
// ============================================================
__global__ void conv_silu_kernel(const float* __restrict__ xz,
                                 const float* __restrict__ w,
                                 const float* __restrict__ b,
                                 float* __restrict__ xconv,
                                 unsigned short* __restrict__ xconv_bf) {
  int idx = blockIdx.x * 256 + threadIdx.x;      // l*DINNER + d
  int d = idx & (DINNER - 1);
  int l = idx >> 11;
  float4 wv = *(const float4*)(w + (size_t)d * 4);
  float wa[4] = {wv.x, wv.y, wv.z, wv.w};
  float acc = b[d];
#pragma unroll
  for (int t = 0; t < 4; t++) {
    int ll = l - 3 + t;
    if (ll >= 0) acc += xz[(size_t)ll * XZDIM + d] * wa[t];
  }
  float s = acc / (1.0f + __expf(-acc));
  xconv[idx] = s;
  xconv_bf[idx] = f2bf(s);
}

// ============================================================
// dt[l][d] = softplus( dt_lr @ dt_proj_w.T + b ), 8 rows/block
// ============================================================
__global__ __launch_bounds__(256) void dt_kernel(
    const float* __restrict__ xdbl, const float* __restrict__ dtw,
    const float* __restrict__ dtb, float* __restrict__ dt) {
  __shared__ float rl[8][RANK];
  int l0 = blockIdx.x * 8;
  int tid = threadIdx.x;
  for (int i = tid; i < 8 * RANK; i += 256) {
    int r = i >> 6, j = i & 63;
    rl[r][j] = xdbl[(size_t)(l0 + r) * NPROJ + j];
  }
  __syncthreads();
  for (int d = tid; d < DINNER; d += 256) {
    float bias = dtb[d];
    float accv[8];
#pragma unroll
    for (int r = 0; r < 8; r++) accv[r] = bias;
    const float4* wr = (const float4*)(dtw + (size_t)d * RANK);
#pragma unroll
    for (int k4 = 0; k4 < 16; k4++) {
      float4 w4 = wr[k4];
#pragma unroll
      for (int r = 0; r < 8; r++)
        accv[r] += rl[r][k4 * 4 + 0] * w4.x + rl[r][k4 * 4 + 1] * w4.y +
                   rl[r][k4 * 4 + 2] * w4.z + rl[r][k4 * 4 + 3] * w4.w;
    }
#pragma unroll
    for (int r = 0; r < 8; r++) {
      float a = accv[r];
      float sp = (a > 20.f) ? a : log1pf(__expf(a));
      dt[(size_t)(l0 + r) * DINNER + d] = sp;
    }
  }
}

// ============================================================
// Scan phase A: per (chunk, channel) local scan, h0 = 0.
// ============================================================
__global__ __launch_bounds__(256) void scan_a_kernel(
    const float* __restrict__ dt, const float* __restrict__ xconv,
    const float* __restrict__ xdbl, const float* __restrict__ A_log,
    float* __restrict__ Pout, float* __restrict__ Hout) {
  __shared__ float Bsm[CHUNK][DSTATE];
  int c = blockIdx.x;
  int d = blockIdx.y * 256 + threadIdx.x;
  for (int i = threadIdx.x; i < CHUNK * DSTATE; i += 256) {
    int l = i >> 4, n = i & 15;
    Bsm[l][n] = xdbl[(size_t)(c * CHUNK + l) * NPROJ + RANK + n];
  }
  __syncthreads();
  float a[16], h[16], P[16];
  const float4* al4 = (const float4*)(A_log + (size_t)d * 16);
#pragma unroll
  for (int q = 0; q < 4; q++) {
    float4 v = al4[q];
    a[q * 4 + 0] = -__expf(v.x); a[q * 4 + 1] = -__expf(v.y);
    a[q * 4 + 2] = -__expf(v.z); a[q * 4 + 3] = -__expf(v.w);
  }
#pragma unroll
  for (int n = 0; n < 16; n++) { h[n] = 0.f; P[n] = 1.f; }
  for (int l = 0; l < CHUNK; l++) {
    int gl = c * CHUNK + l;
    float dtv = dt[(size_t)gl * DINNER + d];
    float xv = xconv[(size_t)gl * DINNER + d];
    float dtx = dtv * xv;
#pragma unroll
    for (int n = 0; n < 16; n++) {
      float dA = __expf(dtv * a[n]);
      P[n] *= dA;
      h[n] = dA * h[n] + dtx * Bsm[l][n];
    }
  }
#pragma unroll
  for (int n = 0; n < 16; n++) {
    size_t o = ((size_t)c * 16 + n) * DINNER + d;
    Pout[o] = P[n];
    Hout[o] = h[n];
  }
}

// ============================================================
// Combine: sequential scan over the NCHUNK chunk boundaries.
// ============================================================
__global__ void combine_kernel(const float* __restrict__ P,
                               const float* __restrict__ Hl,
                               float* __restrict__ H0) {
  int i = blockIdx.x * 256 + threadIdx.x;  // n*DINNER + d
  float h = 0.f;
  for (int c = 0; c < NCHUNK; c++) {
    size_t o = (size_t)c * (DINNER * DSTATE) + i;
    H0[o] = h;
    h = P[o] * h + Hl[o];
  }
}

// ============================================================
// Scan phase C: replay with correct h0, fuse y + D*x + silu(z) gate,
// emit yz directly as bf16 for the out-GEMM.
// ============================================================
__global__ __launch_bounds__(256) void scan_c_kernel(
    const float* __restrict__ dt, const float* __restrict__ xconv,
    const float* __restrict__ xdbl, const float* __restrict__ A_log,
    const float* __restrict__ H0, const float* __restrict__ xz,
    const float* __restrict__ Dp, unsigned short* __restrict__ yzbf) {
  __shared__ float Bsm[CHUNK][DSTATE];
  __shared__ float Csm[CHUNK][DSTATE];
  int c = blockIdx.x;
  int d = blockIdx.y * 256 + threadIdx.x;
  for (int i = threadIdx.x; i < CHUNK * DSTATE; i += 256) {
    int l = i >> 4, n = i & 15;
    size_t base = (size_t)(c * CHUNK + l) * NPROJ + RANK;
    Bsm[l][n] = xdbl[base + n];
    Csm[l][n] = xdbl[base + DSTATE + n];
  }
  __syncthreads();
  float a[16], h[16];
  const float4* al4 = (const float4*)(A_log + (size_t)d * 16);
#pragma unroll
  for (int q = 0; q < 4; q++) {
    float4 v = al4[q];
    a[q * 4 + 0] = -__expf(v.x); a[q * 4 + 1] = -__expf(v.y);
    a[q * 4 + 2] = -__expf(v.z); a[q * 4 + 3] = -__expf(v.w);
  }
#pragma unroll
  for (int n = 0; n < 16; n++)
    h[n] = H0[(size_t)c * (DINNER * DSTATE) + n * DINNER + d];
  float dp = Dp[d];
  for (int l = 0; l < CHUNK; l++) {
    int gl = c * CHUNK + l;
    float dtv = dt[(size_t)gl * DINNER + d];
    float xv = xconv[(size_t)gl * DINNER + d];
    float dtx = dtv * xv;
    float y = 0.f;
#pragma unroll
    for (int n = 0; n < 16; n++) {
      float dA = __expf(dtv * a[n]);
      h[n] = dA * h[n] + dtx * Bsm[l][n];
      y += h[n] * Csm[l][n];
    }
    y += xv * dp;
    float zv = xz[(size_t)gl * XZDIM + DINNER + d];
    float sz = zv / (1.0f + __expf(-zv));
    yzbf[(size_t)gl * DINNER + d] = f2bf(y * sz);
  }
}

// ============================================================
extern "C" void kernel_launch(void* const* d_in, const int* in_sizes, int n_in,
                              void* d_out, int out_size, void* d_ws, size_t ws_size,
                              hipStream_t stream) {
  const float* x          = (const float*)d_in[0];
  const float* in_proj_w  = (const float*)d_in[1];
  const float* conv_w     = (const float*)d_in[2];
  const float* conv_b     = (const float*)d_in[3];
  const float* x_proj_w   = (const float*)d_in[4];
  const float* dt_proj_w  = (const float*)d_in[5];
  const float* dt_proj_b  = (const float*)d_in[6];
  const float* A_log      = (const float*)d_in[7];
  const float* D_param    = (const float*)d_in[8];
  const float* out_proj_w = (const float*)d_in[9];
  float* out = (float*)d_out;

  float* ws = (float*)d_ws;
  float* xz    = ws;                                       // 8,388,608 f
  float* xconv = xz    + (size_t)L_SEQ * XZDIM;            // 4,194,304 f
  float* xdbl  = xconv + (size_t)L_SEQ * DINNER;           //   196,608 f
  float* dt    = xdbl  + (size_t)L_SEQ * NPROJ;            // 4,194,304 f
  float* P     = dt    + (size_t)L_SEQ * DINNER;           // 2,097,152 f
  float* Hl    = P     + (size_t)NCHUNK * DINNER * DSTATE; // 2,097,152 f
  float* H0    = Hl    + (size_t)NCHUNK * DINNER * DSTATE; // 2,097,152 f
  float* Cpart = H0    + (size_t)NCHUNK * DINNER * DSTATE; // 2,097,152 f
  unsigned short* bf = (unsigned short*)(Cpart + (size_t)SPLITK * L_SEQ * NPAD);
  unsigned short* x_bf     = bf;                                 // 2,097,152 e
  unsigned short* win_bf   = x_bf     + (size_t)L_SEQ * DMODEL;   // 4,194,304 e
  unsigned short* wout_bf  = win_bf   + (size_t)XZDIM * DMODEL;   // 2,097,152 e
  unsigned short* yz_bf    = wout_bf  + (size_t)DMODEL * DINNER;  // 4,194,304 e
  unsigned short* xconv_bf = yz_bf    + (size_t)L_SEQ * DINNER;   // 4,194,304 e
  unsigned short* wpad_bf  = xconv_bf + (size_t)L_SEQ * DINNER;   //   262,144 e

  // 0. f32 -> bf16 converts for MFMA operands
  f32_to_bf16_kernel<<<(L_SEQ * DMODEL) / 2048, 256, 0, stream>>>(x, x_bf);
  f32_to_bf16_kernel<<<(XZDIM * DMODEL) / 2048, 256, 0, stream>>>(in_proj_w, win_bf);
  f32_to_bf16_kernel<<<(DMODEL * DINNER) / 2048, 256, 0, stream>>>(out_proj_w, wout_bf);
  pad_convert_xw_kernel<<<(NPAD * DINNER) / 2048, 256, 0, stream>>>(x_proj_w, wpad_bf);

  // 1. xz = x @ in_proj_w.T            (2048 x 4096, K=1024)
  gemm_nt_bf16<<<dim3(XZDIM / 128, L_SEQ / 128), 256, 0, stream>>>(
      x_bf, win_bf, xz, L_SEQ, XZDIM, DMODEL);
  // 2. depthwise conv + SiLU (f32 + bf16)
  conv_silu_kernel<<<(L_SEQ * DINNER) / 256, 256, 0, stream>>>(
      xz, conv_w, conv_b, xconv, xconv_bf);
  // 3. x_dbl = xconv @ x_proj_w.T via split-K MFMA + reduce
  gemm_xdbl_splitk<<<dim3(SPLITK, L_SEQ / 128), 256, 0, stream>>>(
      xconv_bf, wpad_bf, Cpart);
  xdbl_reduce_kernel<<<(L_SEQ * NPROJ) / 256, 256, 0, stream>>>(Cpart, xdbl);
  // 4. dt = softplus(dt_lr @ dt_proj_w.T + b)
  dt_kernel<<<L_SEQ / 8, 256, 0, stream>>>(xdbl, dt_proj_w, dt_proj_b, dt);
  // 5. scan phase A
  scan_a_kernel<<<dim3(NCHUNK, DINNER / 256), 256, 0, stream>>>(
      dt, xconv, xdbl, A_log, P, Hl);
  // 6. combine chunk boundaries
  combine_kernel<<<(DINNER * DSTATE) / 256, 256, 0, stream>>>(P, Hl, H0);
  // 7. scan phase C (replay + gate, bf16 out)
  scan_c_kernel<<<dim3(NCHUNK, DINNER / 256), 256, 0, stream>>>(
      dt, xconv, xdbl, A_log, H0, xz, D_param, yz_bf);
  // 8. out = yz @ out_proj_w.T         (2048 x 1024, K=2048)
  gemm_nt_bf16<<<dim3(DMODEL / 128, L_SEQ / 128), 256, 0, stream>>>(
      yz_bf, wout_bf, out, L_SEQ, DMODEL, DINNER);
}

// Round 8
// 291.352 us; speedup vs baseline: 1.7389x; 1.1547x over previous
//
#include <hip/hip_runtime.h>

// ---- problem constants ----
#define L_SEQ   2048
#define DMODEL  1024
#define DINNER  2048
#define DSTATE  16
#define RANK    64
#define NPROJ   96      // RANK + 2*DSTATE
#define NPAD    128     // padded x_proj rows for MFMA tile
#define XZDIM   4096    // 2*DINNER
#define CHUNK   32
#define NCHUNK  64      // CHUNK*NCHUNK == L_SEQ
#define SPLITK  8       // split-K for the x_dbl GEMM

typedef __bf16 bf16x8 __attribute__((ext_vector_type(8)));
typedef float  f32x4  __attribute__((ext_vector_type(4)));

__device__ __forceinline__ unsigned short f2bf(float f) {
  unsigned int x = __float_as_uint(f);
  x += 0x7FFF + ((x >> 16) & 1);          // round-to-nearest-even
  return (unsigned short)(x >> 16);
}

#define GLD16(g, l)                                                            \
  __builtin_amdgcn_global_load_lds(                                            \
      (const __attribute__((address_space(1))) void*)(g),                      \
      (__attribute__((address_space(3))) void*)(l), 16, 0, 0)

// ============================================================
// f32 -> bf16 convert, 8 elems/thread (n % 2048 == 0)
// ============================================================
__global__ __launch_bounds__(256) void f32_to_bf16_kernel(
    const float* __restrict__ src, unsigned short* __restrict__ dst) {
  size_t i = ((size_t)blockIdx.x * 256 + threadIdx.x) * 8;
  float4 v0 = *(const float4*)(src + i);
  float4 v1 = *(const float4*)(src + i + 4);
  unsigned short o[8];
  o[0] = f2bf(v0.x); o[1] = f2bf(v0.y); o[2] = f2bf(v0.z); o[3] = f2bf(v0.w);
  o[4] = f2bf(v1.x); o[5] = f2bf(v1.y); o[6] = f2bf(v1.z); o[7] = f2bf(v1.w);
  *(ushort4*)(dst + i)     = make_ushort4(o[0], o[1], o[2], o[3]);
  *(ushort4*)(dst + i + 4) = make_ushort4(o[4], o[5], o[6], o[7]);
}

// ============================================================
// x_proj_w (96 x 2048 f32) -> bf16 padded to 128 rows (rows 96+ = 0)
// ============================================================
__global__ __launch_bounds__(256) void pad_convert_xw_kernel(
    const float* __restrict__ src, unsigned short* __restrict__ dst) {
  size_t i = ((size_t)blockIdx.x * 256 + threadIdx.x) * 8;  // over 128*2048
  int row = (int)(i >> 11);
  unsigned short o[8];
  if (row < NPROJ) {
    float4 v0 = *(const float4*)(src + i);
    float4 v1 = *(const float4*)(src + i + 4);
    o[0] = f2bf(v0.x); o[1] = f2bf(v0.y); o[2] = f2bf(v0.z); o[3] = f2bf(v0.w);
    o[4] = f2bf(v1.x); o[5] = f2bf(v1.y); o[6] = f2bf(v1.z); o[7] = f2bf(v1.w);
  } else {
    for (int t = 0; t < 8; t++) o[t] = 0;
  }
  *(ushort4*)(dst + i)     = make_ushort4(o[0], o[1], o[2], o[3]);
  *(ushort4*)(dst + i + 4) = make_ushort4(o[4], o[5], o[6], o[7]);
}

// ============================================================
// bf16 MFMA GEMM (m97 structure):  C[M][N] = A[M][K] * B[N][K]^T
// 128x128 tile, BK=32, 256 thr (4 waves), 4x4 frags 16x16x32.
// ============================================================
__global__ __launch_bounds__(256) void gemm_nt_bf16(
    const unsigned short* __restrict__ A, const unsigned short* __restrict__ B,
    float* __restrict__ C, int M, int N, int K) {
  __shared__ unsigned short As[128 * 32];
  __shared__ unsigned short Bs[128 * 32];
  const int tid  = threadIdx.x;
  const int lane = tid & 63;
  const int wave = tid >> 6;
  const int wr = wave >> 1, wc = wave & 1;
  const int fr = lane & 15;
  const int kq = (lane >> 4) * 8;
  const size_t bm = blockIdx.y, bn = blockIdx.x;

  f32x4 acc[4][4] = {};

  const int q0 = tid, q1 = tid + 256;
  const unsigned short* a0 = A + (bm * 128 + (q0 >> 2)) * (size_t)K + (q0 & 3) * 8;
  const unsigned short* a1 = A + (bm * 128 + (q1 >> 2)) * (size_t)K + (q1 & 3) * 8;
  const unsigned short* b0 = B + (bn * 128 + (q0 >> 2)) * (size_t)K + (q0 & 3) * 8;
  const unsigned short* b1 = B + (bn * 128 + (q1 >> 2)) * (size_t)K + (q1 & 3) * 8;

  for (int k0 = 0; k0 < K; k0 += 32) {
    GLD16(a0 + k0, &As[q0 * 8]);
    GLD16(a1 + k0, &As[q1 * 8]);
    GLD16(b0 + k0, &Bs[q0 * 8]);
    GLD16(b1 + k0, &Bs[q1 * 8]);
    __syncthreads();
    bf16x8 af[4], bg[4];
#pragma unroll
    for (int m = 0; m < 4; m++)
      af[m] = *(const bf16x8*)&As[(wr * 64 + m * 16 + fr) * 32 + kq];
#pragma unroll
    for (int n = 0; n < 4; n++)
      bg[n] = *(const bf16x8*)&Bs[(wc * 64 + n * 16 + fr) * 32 + kq];
#pragma unroll
    for (int m = 0; m < 4; m++)
#pragma unroll
      for (int n = 0; n < 4; n++)
        acc[m][n] = __builtin_amdgcn_mfma_f32_16x16x32_bf16(af[m], bg[n],
                                                            acc[m][n], 0, 0, 0);
    __syncthreads();
  }
  const int cr = (lane >> 4) * 4;    // C/D: col=lane&15, row=(lane>>4)*4+reg
#pragma unroll
  for (int m = 0; m < 4; m++)
#pragma unroll
    for (int n = 0; n < 4; n++) {
      float* cp = C + (bm * 128 + wr * 64 + m * 16 + cr) * (size_t)N +
                  bn * 128 + wc * 64 + n * 16 + fr;
#pragma unroll
      for (int r = 0; r < 4; r++) cp[(size_t)r * N] = acc[m][n][r];
    }
}

// ============================================================
// dt GEMM (K=64) + fused bias + softplus:
// dt[l][d] = softplus( dtlr[l][:] . dtw[d][:] + dtb[d] )
// Same 128x128 MFMA structure, 2 K-steps.
// ============================================================
__global__ __launch_bounds__(256) void gemm_dt_bf16(
    const unsigned short* __restrict__ A,   // dtlr_bf [L_SEQ][64]
    const unsigned short* __restrict__ B,   // dtw_bf  [DINNER][64]
    const float* __restrict__ bias,         // dtb [DINNER]
    float* __restrict__ dt) {               // [L_SEQ][DINNER]
  __shared__ unsigned short As[128 * 32];
  __shared__ unsigned short Bs[128 * 32];
  const int K = RANK;  // 64
  const int tid  = threadIdx.x;
  const int lane = tid & 63;
  const int wave = tid >> 6;
  const int wr = wave >> 1, wc = wave & 1;
  const int fr = lane & 15;
  const int kq = (lane >> 4) * 8;
  const size_t bm = blockIdx.y, bn = blockIdx.x;

  f32x4 acc[4][4] = {};

  const int q0 = tid, q1 = tid + 256;
  const unsigned short* a0 = A + (bm * 128 + (q0 >> 2)) * (size_t)K + (q0 & 3) * 8;
  const unsigned short* a1 = A + (bm * 128 + (q1 >> 2)) * (size_t)K + (q1 & 3) * 8;
  const unsigned short* b0 = B + (bn * 128 + (q0 >> 2)) * (size_t)K + (q0 & 3) * 8;
  const unsigned short* b1 = B + (bn * 128 + (q1 >> 2)) * (size_t)K + (q1 & 3) * 8;

  for (int k0 = 0; k0 < K; k0 += 32) {
    GLD16(a0 + k0, &As[q0 * 8]);
    GLD16(a1 + k0, &As[q1 * 8]);
    GLD16(b0 + k0, &Bs[q0 * 8]);
    GLD16(b1 + k0, &Bs[q1 * 8]);
    __syncthreads();
    bf16x8 af[4], bg[4];
#pragma unroll
    for (int m = 0; m < 4; m++)
      af[m] = *(const bf16x8*)&As[(wr * 64 + m * 16 + fr) * 32 + kq];
#pragma unroll
    for (int n = 0; n < 4; n++)
      bg[n] = *(const bf16x8*)&Bs[(wc * 64 + n * 16 + fr) * 32 + kq];
#pragma unroll
    for (int m = 0; m < 4; m++)
#pragma unroll
      for (int n = 0; n < 4; n++)
        acc[m][n] = __builtin_amdgcn_mfma_f32_16x16x32_bf16(af[m], bg[n],
                                                            acc[m][n], 0, 0, 0);
    __syncthreads();
  }
  const int cr = (lane >> 4) * 4;
#pragma unroll
  for (int n = 0; n < 4; n++) {
    int col = (int)bn * 128 + wc * 64 + n * 16 + fr;
    float bv = bias[col];
#pragma unroll
    for (int m = 0; m < 4; m++) {
      float* cp = dt + ((size_t)bm * 128 + wr * 64 + m * 16 + cr) * DINNER + col;
#pragma unroll
      for (int r = 0; r < 4; r++) {
        float a = acc[m][n][r] + bv;
        cp[(size_t)r * DINNER] = (a > 20.f) ? a : log1pf(__expf(a));
      }
    }
  }
}

// ============================================================
// Split-K GEMM for x_dbl: A = xconv_bf (2048 x 2048), B = wpad_bf
// (128 x 2048). grid (SPLITK, M/128); writes f32 partials.
// ============================================================
__global__ __launch_bounds__(256) void gemm_xdbl_splitk(
    const unsigned short* __restrict__ A, const unsigned short* __restrict__ B,
    float* __restrict__ Cp) {
  __shared__ unsigned short As[128 * 32];
  __shared__ unsigned short Bs[128 * 32];
  const int K = DINNER;
  const int tid  = threadIdx.x;
  const int lane = tid & 63;
  const int wave = tid >> 6;
  const int wr = wave >> 1, wc = wave & 1;
  const int fr = lane & 15;
  const int kq = (lane >> 4) * 8;
  const int s = blockIdx.x;
  const size_t bm = blockIdx.y;

  f32x4 acc[4][4] = {};

  const int q0 = tid, q1 = tid + 256;
  const unsigned short* a0 = A + (bm * 128 + (q0 >> 2)) * (size_t)K + (q0 & 3) * 8;
  const unsigned short* a1 = A + (bm * 128 + (q1 >> 2)) * (size_t)K + (q1 & 3) * 8;
  const unsigned short* b0 = B + ((size_t)(q0 >> 2)) * K + (q0 & 3) * 8;
  const unsigned short* b1 = B + ((size_t)(q1 >> 2)) * K + (q1 & 3) * 8;

  const int kbeg = s * (DINNER / SPLITK), kend = kbeg + DINNER / SPLITK;
  for (int k0 = kbeg; k0 < kend; k0 += 32) {
    GLD16(a0 + k0, &As[q0 * 8]);
    GLD16(a1 + k0, &As[q1 * 8]);
    GLD16(b0 + k0, &Bs[q0 * 8]);
    GLD16(b1 + k0, &Bs[q1 * 8]);
    __syncthreads();
    bf16x8 af[4], bg[4];
#pragma unroll
    for (int m = 0; m < 4; m++)
      af[m] = *(const bf16x8*)&As[(wr * 64 + m * 16 + fr) * 32 + kq];
#pragma unroll
    for (int n = 0; n < 4; n++)
      bg[n] = *(const bf16x8*)&Bs[(wc * 64 + n * 16 + fr) * 32 + kq];
#pragma unroll
    for (int m = 0; m < 4; m++)
#pragma unroll
      for (int n = 0; n < 4; n++)
        acc[m][n] = __builtin_amdgcn_mfma_f32_16x16x32_bf16(af[m], bg[n],
                                                            acc[m][n], 0, 0, 0);
    __syncthreads();
  }
  const int cr = (lane >> 4) * 4;
  float* Cs = Cp + (size_t)s * L_SEQ * NPAD;
#pragma unroll
  for (int m = 0; m < 4; m++)
#pragma unroll
    for (int n = 0; n < 4; n++) {
      float* cp = Cs + (bm * 128 + wr * 64 + m * 16 + cr) * (size_t)NPAD +
                  wc * 64 + n * 16 + fr;
#pragma unroll
      for (int r = 0; r < 4; r++) cp[(size_t)r * NPAD] = acc[m][n][r];
    }
}

// ============================================================
// Reduce split-K partials -> xdbl[l][96] f32 + dtlr_bf[l][64] bf16
// ============================================================
__global__ __launch_bounds__(256) void xdbl_reduce_kernel(
    const float* __restrict__ Cp, float* __restrict__ xdbl,
    unsigned short* __restrict__ dtlr_bf) {
  int i = blockIdx.x * 256 + threadIdx.x;    // 0 .. L_SEQ*NPROJ-1
  int l = i / NPROJ, j = i - l * NPROJ;
  float s = 0.f;
#pragma unroll
  for (int t = 0; t < SPLITK; t++)
    s += Cp[((size_t)t * L_SEQ + l) * NPAD + j];
  xdbl[i] = s;
  if (j < RANK) dtlr_bf[(size_t)l * RANK + j] = f2bf(s);
}

// ============================================================
// Depthwise causal conv (k=4) + bias + SiLU. f32 + bf16 outputs.
// ============================================================
__global__ void conv_silu_kernel(const float* __restrict__ xz,
                                 const float* __restrict__ w,
                                 const float* __restrict__ b,
                                 float* __restrict__ xconv,
                                 unsigned short* __restrict__ xconv_bf) {
  int idx = blockIdx.x * 256 + threadIdx.x;      // l*DINNER + d
  int d = idx & (DINNER - 1);
  int l = idx >> 11;
  float4 wv = *(const float4*)(w + (size_t)d * 4);
  float wa[4] = {wv.x, wv.y, wv.z, wv.w};
  float acc = b[d];
#pragma unroll
  for (int t = 0; t < 4; t++) {
    int ll = l - 3 + t;
    if (ll >= 0) acc += xz[(size_t)ll * XZDIM + d] * wa[t];
  }
  float s = acc / (1.0f + __expf(-acc));
  xconv[idx] = s;
  xconv_bf[idx] = f2bf(s);
}

// ============================================================
// Scan phase A: per (chunk, channel) local scan, h0 = 0.
// ============================================================
__global__ __launch_bounds__(256) void scan_a_kernel(
    const float* __restrict__ dt, const float* __restrict__ xconv,
    const float* __restrict__ xdbl, const float* __restrict__ A_log,
    float* __restrict__ Pout, float* __restrict__ Hout) {
  __shared__ float Bsm[CHUNK][DSTATE];
  int c = blockIdx.x;
  int d = blockIdx.y * 256 + threadIdx.x;
  for (int i = threadIdx.x; i < CHUNK * DSTATE; i += 256) {
    int l = i >> 4, n = i & 15;
    Bsm[l][n] = xdbl[(size_t)(c * CHUNK + l) * NPROJ + RANK + n];
  }
  __syncthreads();
  float a[16], h[16], P[16];
  const float4* al4 = (const float4*)(A_log + (size_t)d * 16);
#pragma unroll
  for (int q = 0; q < 4; q++) {
    float4 v = al4[q];
    a[q * 4 + 0] = -__expf(v.x); a[q * 4 + 1] = -__expf(v.y);
    a[q * 4 + 2] = -__expf(v.z); a[q * 4 + 3] = -__expf(v.w);
  }
#pragma unroll
  for (int n = 0; n < 16; n++) { h[n] = 0.f; P[n] = 1.f; }
  for (int l = 0; l < CHUNK; l++) {
    int gl = c * CHUNK + l;
    float dtv = dt[(size_t)gl * DINNER + d];
    float xv = xconv[(size_t)gl * DINNER + d];
    float dtx = dtv * xv;
#pragma unroll
    for (int n = 0; n < 16; n++) {
      float dA = __expf(dtv * a[n]);
      P[n] *= dA;
      h[n] = dA * h[n] + dtx * Bsm[l][n];
    }
  }
#pragma unroll
  for (int n = 0; n < 16; n++) {
    size_t o = ((size_t)c * 16 + n) * DINNER + d;
    Pout[o] = P[n];
    Hout[o] = h[n];
  }
}

// ============================================================
// Combine: sequential scan over the NCHUNK chunk boundaries.
// ============================================================
__global__ void combine_kernel(const float* __restrict__ P,
                               const float* __restrict__ Hl,
                               float* __restrict__ H0) {
  int i = blockIdx.x * 256 + threadIdx.x;  // n*DINNER + d
  float h = 0.f;
  for (int c = 0; c < NCHUNK; c++) {
    size_t o = (size_t)c * (DINNER * DSTATE) + i;
    H0[o] = h;
    h = P[o] * h + Hl[o];
  }
}

// ============================================================
// Scan phase C: replay with correct h0, fuse y + D*x + silu(z) gate,
// emit yz directly as bf16 for the out-GEMM.
// ============================================================
__global__ __launch_bounds__(256) void scan_c_kernel(
    const float* __restrict__ dt, const float* __restrict__ xconv,
    const float* __restrict__ xdbl, const float* __restrict__ A_log,
    const float* __restrict__ H0, const float* __restrict__ xz,
    const float* __restrict__ Dp, unsigned short* __restrict__ yzbf) {
  __shared__ float Bsm[CHUNK][DSTATE];
  __shared__ float Csm[CHUNK][DSTATE];
  int c = blockIdx.x;
  int d = blockIdx.y * 256 + threadIdx.x;
  for (int i = threadIdx.x; i < CHUNK * DSTATE; i += 256) {
    int l = i >> 4, n = i & 15;
    size_t base = (size_t)(c * CHUNK + l) * NPROJ + RANK;
    Bsm[l][n] = xdbl[base + n];
    Csm[l][n] = xdbl[base + DSTATE + n];
  }
  __syncthreads();
  float a[16], h[16];
  const float4* al4 = (const float4*)(A_log + (size_t)d * 16);
#pragma unroll
  for (int q = 0; q < 4; q++) {
    float4 v = al4[q];
    a[q * 4 + 0] = -__expf(v.x); a[q * 4 + 1] = -__expf(v.y);
    a[q * 4 + 2] = -__expf(v.z); a[q * 4 + 3] = -__expf(v.w);
  }
#pragma unroll
  for (int n = 0; n < 16; n++)
    h[n] = H0[(size_t)c * (DINNER * DSTATE) + n * DINNER + d];
  float dp = Dp[d];
  for (int l = 0; l < CHUNK; l++) {
    int gl = c * CHUNK + l;
    float dtv = dt[(size_t)gl * DINNER + d];
    float xv = xconv[(size_t)gl * DINNER + d];
    float dtx = dtv * xv;
    float y = 0.f;
#pragma unroll
    for (int n = 0; n < 16; n++) {
      float dA = __expf(dtv * a[n]);
      h[n] = dA * h[n] + dtx * Bsm[l][n];
      y += h[n] * Csm[l][n];
    }
    y += xv * dp;
    float zv = xz[(size_t)gl * XZDIM + DINNER + d];
    float sz = zv / (1.0f + __expf(-zv));
    yzbf[(size_t)gl * DINNER + d] = f2bf(y * sz);
  }
}

// ============================================================
extern "C" void kernel_launch(void* const* d_in, const int* in_sizes, int n_in,
                              void* d_out, int out_size, void* d_ws, size_t ws_size,
                              hipStream_t stream) {
  const float* x          = (const float*)d_in[0];
  const float* in_proj_w  = (const float*)d_in[1];
  const float* conv_w     = (const float*)d_in[2];
  const float* conv_b     = (const float*)d_in[3];
  const float* x_proj_w   = (const float*)d_in[4];
  const float* dt_proj_w  = (const float*)d_in[5];
  const float* dt_proj_b  = (const float*)d_in[6];
  const float* A_log      = (const float*)d_in[7];
  const float* D_param    = (const float*)d_in[8];
  const float* out_proj_w = (const float*)d_in[9];
  float* out = (float*)d_out;

  float* ws = (float*)d_ws;
  float* xz    = ws;                                       // 8,388,608 f
  float* xconv = xz    + (size_t)L_SEQ * XZDIM;            // 4,194,304 f
  float* xdbl  = xconv + (size_t)L_SEQ * DINNER;           //   196,608 f
  float* dt    = xdbl  + (size_t)L_SEQ * NPROJ;            // 4,194,304 f
  float* P     = dt    + (size_t)L_SEQ * DINNER;           // 2,097,152 f
  float* Hl    = P     + (size_t)NCHUNK * DINNER * DSTATE; // 2,097,152 f
  float* H0    = Hl    + (size_t)NCHUNK * DINNER * DSTATE; // 2,097,152 f
  float* Cpart = H0    + (size_t)NCHUNK * DINNER * DSTATE; // 2,097,152 f
  unsigned short* bf = (unsigned short*)(Cpart + (size_t)SPLITK * L_SEQ * NPAD);
  unsigned short* x_bf     = bf;                                 // 2,097,152 e
  unsigned short* win_bf   = x_bf     + (size_t)L_SEQ * DMODEL;   // 4,194,304 e
  unsigned short* wout_bf  = win_bf   + (size_t)XZDIM * DMODEL;   // 2,097,152 e
  unsigned short* yz_bf    = wout_bf  + (size_t)DMODEL * DINNER;  // 4,194,304 e
  unsigned short* xconv_bf = yz_bf    + (size_t)L_SEQ * DINNER;   // 4,194,304 e
  unsigned short* wpad_bf  = xconv_bf + (size_t)L_SEQ * DINNER;   //   262,144 e
  unsigned short* dtlr_bf  = wpad_bf  + (size_t)NPAD * DINNER;    //   131,072 e
  unsigned short* dtw_bf   = dtlr_bf  + (size_t)L_SEQ * RANK;     //   131,072 e

  // 0. f32 -> bf16 converts for MFMA operands
  f32_to_bf16_kernel<<<(L_SEQ * DMODEL) / 2048, 256, 0, stream>>>(x, x_bf);
  f32_to_bf16_kernel<<<(XZDIM * DMODEL) / 2048, 256, 0, stream>>>(in_proj_w, win_bf);
  f32_to_bf16_kernel<<<(DMODEL * DINNER) / 2048, 256, 0, stream>>>(out_proj_w, wout_bf);
  f32_to_bf16_kernel<<<(DINNER * RANK) / 2048, 256, 0, stream>>>(dt_proj_w, dtw_bf);
  pad_convert_xw_kernel<<<(NPAD * DINNER) / 2048, 256, 0, stream>>>(x_proj_w, wpad_bf);

  // 1. xz = x @ in_proj_w.T            (2048 x 4096, K=1024)
  gemm_nt_bf16<<<dim3(XZDIM / 128, L_SEQ / 128), 256, 0, stream>>>(
      x_bf, win_bf, xz, L_SEQ, XZDIM, DMODEL);
  // 2. depthwise conv + SiLU (f32 + bf16)
  conv_silu_kernel<<<(L_SEQ * DINNER) / 256, 256, 0, stream>>>(
      xz, conv_w, conv_b, xconv, xconv_bf);
  // 3. x_dbl = xconv @ x_proj_w.T via split-K MFMA + reduce (emits dtlr bf16)
  gemm_xdbl_splitk<<<dim3(SPLITK, L_SEQ / 128), 256, 0, stream>>>(
      xconv_bf, wpad_bf, Cpart);
  xdbl_reduce_kernel<<<(L_SEQ * NPROJ) / 256, 256, 0, stream>>>(
      Cpart, xdbl, dtlr_bf);
  // 4. dt = softplus(dt_lr @ dt_proj_w.T + b) via MFMA (K=64), fused epilogue
  gemm_dt_bf16<<<dim3(DINNER / 128, L_SEQ / 128), 256, 0, stream>>>(
      dtlr_bf, dtw_bf, dt_proj_b, dt);
  // 5. scan phase A
  scan_a_kernel<<<dim3(NCHUNK, DINNER / 256), 256, 0, stream>>>(
      dt, xconv, xdbl, A_log, P, Hl);
  // 6. combine chunk boundaries
  combine_kernel<<<(DINNER * DSTATE) / 256, 256, 0, stream>>>(P, Hl, H0);
  // 7. scan phase C (replay + gate, bf16 out)
  scan_c_kernel<<<dim3(NCHUNK, DINNER / 256), 256, 0, stream>>>(
      dt, xconv, xdbl, A_log, H0, xz, D_param, yz_bf);
  // 8. out = yz @ out_proj_w.T         (2048 x 1024, K=2048)
  gemm_nt_bf16<<<dim3(DMODEL / 128, L_SEQ / 128), 256, 0, stream>>>(
      yz_bf, wout_bf, out, L_SEQ, DMODEL, DINNER);
}

// Round 10
// 270.819 us; speedup vs baseline: 1.8708x; 1.0758x over previous
//
#include <hip/hip_runtime.h>

// ---- problem constants ----
#define L_SEQ   2048
#define DMODEL  1024
#define DINNER  2048
#define DSTATE  16
#define RANK    64
#define NPROJ   96      // RANK + 2*DSTATE
#define NPAD    128     // padded x_proj rows for MFMA tile
#define XZDIM   4096    // 2*DINNER
#define CHUNK   32
#define NCHUNK  64      // CHUNK*NCHUNK == L_SEQ
#define SPLITK  8       // split-K for the x_dbl GEMM

typedef __bf16 bf16x8 __attribute__((ext_vector_type(8)));
typedef float  f32x4  __attribute__((ext_vector_type(4)));

__device__ __forceinline__ unsigned short f2bf(float f) {
  unsigned int x = __float_as_uint(f);
  x += 0x7FFF + ((x >> 16) & 1);          // round-to-nearest-even
  return (unsigned short)(x >> 16);
}

#define GLD16(g, l)                                                            \
  __builtin_amdgcn_global_load_lds(                                            \
      (const __attribute__((address_space(1))) void*)(g),                      \
      (__attribute__((address_space(3))) void*)(l), 16, 0, 0)

// ============================================================
// f32 -> bf16 convert, 8 elems/thread (n % 2048 == 0)
// ============================================================
__global__ __launch_bounds__(256) void f32_to_bf16_kernel(
    const float* __restrict__ src, unsigned short* __restrict__ dst) {
  size_t i = ((size_t)blockIdx.x * 256 + threadIdx.x) * 8;
  float4 v0 = *(const float4*)(src + i);
  float4 v1 = *(const float4*)(src + i + 4);
  unsigned short o[8];
  o[0] = f2bf(v0.x); o[1] = f2bf(v0.y); o[2] = f2bf(v0.z); o[3] = f2bf(v0.w);
  o[4] = f2bf(v1.x); o[5] = f2bf(v1.y); o[6] = f2bf(v1.z); o[7] = f2bf(v1.w);
  *(ushort4*)(dst + i)     = make_ushort4(o[0], o[1], o[2], o[3]);
  *(ushort4*)(dst + i + 4) = make_ushort4(o[4], o[5], o[6], o[7]);
}

// ============================================================
// x_proj_w (96 x 2048 f32) -> bf16 padded to 128 rows (rows 96+ = 0)
// ============================================================
__global__ __launch_bounds__(256) void pad_convert_xw_kernel(
    const float* __restrict__ src, unsigned short* __restrict__ dst) {
  size_t i = ((size_t)blockIdx.x * 256 + threadIdx.x) * 8;  // over 128*2048
  int row = (int)(i >> 11);
  unsigned short o[8];
  if (row < NPROJ) {
    float4 v0 = *(const float4*)(src + i);
    float4 v1 = *(const float4*)(src + i + 4);
    o[0] = f2bf(v0.x); o[1] = f2bf(v0.y); o[2] = f2bf(v0.z); o[3] = f2bf(v0.w);
    o[4] = f2bf(v1.x); o[5] = f2bf(v1.y); o[6] = f2bf(v1.z); o[7] = f2bf(v1.w);
  } else {
    for (int t = 0; t < 8; t++) o[t] = 0;
  }
  *(ushort4*)(dst + i)     = make_ushort4(o[0], o[1], o[2], o[3]);
  *(ushort4*)(dst + i + 4) = make_ushort4(o[4], o[5], o[6], o[7]);
}

// ============================================================
// Templated bf16 MFMA GEMM:  C[M][N] = A[M][K] * B[N][K]^T
// BMxBN tile, BK=32, 256 thr (4 waves as (BM/WM)x(BN/WN)),
// each wave WMxWN via (WM/16)x(WN/16) frags of 16x16x32.
// Smaller tiles -> more blocks -> occupancy for skinny GEMMs.
// ============================================================
template <int BM, int BN, int WM, int WN>
__global__ __launch_bounds__(256) void gemm_tile(
    const unsigned short* __restrict__ A, const unsigned short* __restrict__ B,
    float* __restrict__ C, int M, int N, int K) {
  constexpr int WGN = BN / WN;          // waves along N
  constexpr int FM = WM / 16, FN = WN / 16;
  constexpr int CA = BM * 4 / 256;      // A 16B-chunks per thread
  constexpr int CB = BN * 4 / 256;      // B 16B-chunks per thread
  __shared__ unsigned short As[BM * 32];
  __shared__ unsigned short Bs[BN * 32];
  const int tid  = threadIdx.x;
  const int lane = tid & 63;
  const int wave = tid >> 6;
  const int wr = wave / WGN, wc = wave % WGN;
  const int fr = lane & 15;
  const int kq = (lane >> 4) * 8;
  const size_t bm = blockIdx.y, bn = blockIdx.x;

  f32x4 acc[FM][FN] = {};

  const unsigned short* aptr[CA];
  const unsigned short* bptr[CB];
#pragma unroll
  for (int i = 0; i < CA; i++) {
    int q = tid + i * 256;
    aptr[i] = A + (bm * BM + (q >> 2)) * (size_t)K + (q & 3) * 8;
  }
#pragma unroll
  for (int i = 0; i < CB; i++) {
    int q = tid + i * 256;
    bptr[i] = B + (bn * BN + (q >> 2)) * (size_t)K + (q & 3) * 8;
  }

  for (int k0 = 0; k0 < K; k0 += 32) {
#pragma unroll
    for (int i = 0; i < CA; i++) GLD16(aptr[i] + k0, &As[(tid + i * 256) * 8]);
#pragma unroll
    for (int i = 0; i < CB; i++) GLD16(bptr[i] + k0, &Bs[(tid + i * 256) * 8]);
    __syncthreads();                 // drains vmcnt before LDS reads
    bf16x8 af[FM], bg[FN];
#pragma unroll
    for (int m = 0; m < FM; m++)
      af[m] = *(const bf16x8*)&As[(wr * WM + m * 16 + fr) * 32 + kq];
#pragma unroll
    for (int n = 0; n < FN; n++)
      bg[n] = *(const bf16x8*)&Bs[(wc * WN + n * 16 + fr) * 32 + kq];
#pragma unroll
    for (int m = 0; m < FM; m++)
#pragma unroll
      for (int n = 0; n < FN; n++)
        acc[m][n] = __builtin_amdgcn_mfma_f32_16x16x32_bf16(af[m], bg[n],
                                                            acc[m][n], 0, 0, 0);
    __syncthreads();                 // protect LDS before next stage
  }
  const int cr = (lane >> 4) * 4;    // C/D: col=lane&15, row=(lane>>4)*4+reg
#pragma unroll
  for (int m = 0; m < FM; m++)
#pragma unroll
    for (int n = 0; n < FN; n++) {
      float* cp = C + (bm * BM + wr * WM + m * 16 + cr) * (size_t)N +
                  bn * BN + wc * WN + n * 16 + fr;
#pragma unroll
      for (int r = 0; r < 4; r++) cp[(size_t)r * N] = acc[m][n][r];
    }
}

// ============================================================
// dt GEMM (K=64) + fused bias + softplus:
// dt[l][d] = softplus( dtlr[l][:] . dtw[d][:] + dtb[d] )
// 128x128 MFMA structure, 2 K-steps.
// ============================================================
__global__ __launch_bounds__(256) void gemm_dt_bf16(
    const unsigned short* __restrict__ A,   // dtlr_bf [L_SEQ][64]
    const unsigned short* __restrict__ B,   // dtw_bf  [DINNER][64]
    const float* __restrict__ bias,         // dtb [DINNER]
    float* __restrict__ dt) {               // [L_SEQ][DINNER]
  __shared__ unsigned short As[128 * 32];
  __shared__ unsigned short Bs[128 * 32];
  const int K = RANK;  // 64
  const int tid  = threadIdx.x;
  const int lane = tid & 63;
  const int wave = tid >> 6;
  const int wr = wave >> 1, wc = wave & 1;
  const int fr = lane & 15;
  const int kq = (lane >> 4) * 8;
  const size_t bm = blockIdx.y, bn = blockIdx.x;

  f32x4 acc[4][4] = {};

  const int q0 = tid, q1 = tid + 256;
  const unsigned short* a0 = A + (bm * 128 + (q0 >> 2)) * (size_t)K + (q0 & 3) * 8;
  const unsigned short* a1 = A + (bm * 128 + (q1 >> 2)) * (size_t)K + (q1 & 3) * 8;
  const unsigned short* b0 = B + (bn * 128 + (q0 >> 2)) * (size_t)K + (q0 & 3) * 8;
  const unsigned short* b1 = B + (bn * 128 + (q1 >> 2)) * (size_t)K + (q1 & 3) * 8;

  for (int k0 = 0; k0 < K; k0 += 32) {
    GLD16(a0 + k0, &As[q0 * 8]);
    GLD16(a1 + k0, &As[q1 * 8]);
    GLD16(b0 + k0, &Bs[q0 * 8]);
    GLD16(b1 + k0, &Bs[q1 * 8]);
    __syncthreads();
    bf16x8 af[4], bg[4];
#pragma unroll
    for (int m = 0; m < 4; m++)
      af[m] = *(const bf16x8*)&As[(wr * 64 + m * 16 + fr) * 32 + kq];
#pragma unroll
    for (int n = 0; n < 4; n++)
      bg[n] = *(const bf16x8*)&Bs[(wc * 64 + n * 16 + fr) * 32 + kq];
#pragma unroll
    for (int m = 0; m < 4; m++)
#pragma unroll
      for (int n = 0; n < 4; n++)
        acc[m][n] = __builtin_amdgcn_mfma_f32_16x16x32_bf16(af[m], bg[n],
                                                            acc[m][n], 0, 0, 0);
    __syncthreads();
  }
  const int cr = (lane >> 4) * 4;
#pragma unroll
  for (int n = 0; n < 4; n++) {
    int col = (int)bn * 128 + wc * 64 + n * 16 + fr;
    float bv = bias[col];
#pragma unroll
    for (int m = 0; m < 4; m++) {
      float* cp = dt + ((size_t)bm * 128 + wr * 64 + m * 16 + cr) * DINNER + col;
#pragma unroll
      for (int r = 0; r < 4; r++) {
        float a = acc[m][n][r] + bv;
        cp[(size_t)r * DINNER] = (a > 20.f) ? a : log1pf(__expf(a));
      }
    }
  }
}

// ============================================================
// Split-K GEMM for x_dbl: A = xconv_bf (2048 x 2048), B = wpad_bf
// (128 x 2048). grid (SPLITK, M/128); writes f32 partials.
// ============================================================
__global__ __launch_bounds__(256) void gemm_xdbl_splitk(
    const unsigned short* __restrict__ A, const unsigned short* __restrict__ B,
    float* __restrict__ Cp) {
  __shared__ unsigned short As[128 * 32];
  __shared__ unsigned short Bs[128 * 32];
  const int K = DINNER;
  const int tid  = threadIdx.x;
  const int lane = tid & 63;
  const int wave = tid >> 6;
  const int wr = wave >> 1, wc = wave & 1;
  const int fr = lane & 15;
  const int kq = (lane >> 4) * 8;
  const int s = blockIdx.x;
  const size_t bm = blockIdx.y;

  f32x4 acc[4][4] = {};

  const int q0 = tid, q1 = tid + 256;
  const unsigned short* a0 = A + (bm * 128 + (q0 >> 2)) * (size_t)K + (q0 & 3) * 8;
  const unsigned short* a1 = A + (bm * 128 + (q1 >> 2)) * (size_t)K + (q1 & 3) * 8;
  const unsigned short* b0 = B + ((size_t)(q0 >> 2)) * K + (q0 & 3) * 8;
  const unsigned short* b1 = B + ((size_t)(q1 >> 2)) * K + (q1 & 3) * 8;

  const int kbeg = s * (DINNER / SPLITK), kend = kbeg + DINNER / SPLITK;
  for (int k0 = kbeg; k0 < kend; k0 += 32) {
    GLD16(a0 + k0, &As[q0 * 8]);
    GLD16(a1 + k0, &As[q1 * 8]);
    GLD16(b0 + k0, &Bs[q0 * 8]);
    GLD16(b1 + k0, &Bs[q1 * 8]);
    __syncthreads();
    bf16x8 af[4], bg[4];
#pragma unroll
    for (int m = 0; m < 4; m++)
      af[m] = *(const bf16x8*)&As[(wr * 64 + m * 16 + fr) * 32 + kq];
#pragma unroll
    for (int n = 0; n < 4; n++)
      bg[n] = *(const bf16x8*)&Bs[(wc * 64 + n * 16 + fr) * 32 + kq];
#pragma unroll
    for (int m = 0; m < 4; m++)
#pragma unroll
      for (int n = 0; n < 4; n++)
        acc[m][n] = __builtin_amdgcn_mfma_f32_16x16x32_bf16(af[m], bg[n],
                                                            acc[m][n], 0, 0, 0);
    __syncthreads();
  }
  const int cr = (lane >> 4) * 4;
  float* Cs = Cp + (size_t)s * L_SEQ * NPAD;
#pragma unroll
  for (int m = 0; m < 4; m++)
#pragma unroll
    for (int n = 0; n < 4; n++) {
      float* cp = Cs + (bm * 128 + wr * 64 + m * 16 + cr) * (size_t)NPAD +
                  wc * 64 + n * 16 + fr;
#pragma unroll
      for (int r = 0; r < 4; r++) cp[(size_t)r * NPAD] = acc[m][n][r];
    }
}

// ============================================================
// Reduce split-K partials -> xdbl[l][96] f32 + dtlr_bf[l][64] bf16
// ============================================================
__global__ __launch_bounds__(256) void xdbl_reduce_kernel(
    const float* __restrict__ Cp, float* __restrict__ xdbl,
    unsigned short* __restrict__ dtlr_bf) {
  int i = blockIdx.x * 256 + threadIdx.x;    // 0 .. L_SEQ*NPROJ-1
  int l = i / NPROJ, j = i - l * NPROJ;
  float s = 0.f;
#pragma unroll
  for (int t = 0; t < SPLITK; t++)
    s += Cp[((size_t)t * L_SEQ + l) * NPAD + j];
  xdbl[i] = s;
  if (j < RANK) dtlr_bf[(size_t)l * RANK + j] = f2bf(s);
}

// ============================================================
// Depthwise causal conv (k=4) + bias + SiLU. f32 + bf16 outputs.
// ============================================================
__global__ void conv_silu_kernel(const float* __restrict__ xz,
                                 const float* __restrict__ w,
                                 const float* __restrict__ b,
                                 float* __restrict__ xconv,
                                 unsigned short* __restrict__ xconv_bf) {
  int idx = blockIdx.x * 256 + threadIdx.x;      // l*DINNER + d
  int d = idx & (DINNER - 1);
  int l = idx >> 11;
  float4 wv = *(const float4*)(w + (size_t)d * 4);
  float wa[4] = {wv.x, wv.y, wv.z, wv.w};
  float acc = b[d];
#pragma unroll
  for (int t = 0; t < 4; t++) {
    int ll = l - 3 + t;
    if (ll >= 0) acc += xz[(size_t)ll * XZDIM + d] * wa[t];
  }
  float s = acc / (1.0f + __expf(-acc));
  xconv[idx] = s;
  xconv_bf[idx] = f2bf(s);
}

// ============================================================
// Scan phase A: per (chunk, channel) local scan, h0 = 0.
// ============================================================
__global__ __launch_bounds__(256) void scan_a_kernel(
    const float* __restrict__ dt, const float* __restrict__ xconv,
    const float* __restrict__ xdbl, const float* __restrict__ A_log,
    float* __restrict__ Pout, float* __restrict__ Hout) {
  __shared__ float Bsm[CHUNK][DSTATE];
  int c = blockIdx.x;
  int d = blockIdx.y * 256 + threadIdx.x;
  for (int i = threadIdx.x; i < CHUNK * DSTATE; i += 256) {
    int l = i >> 4, n = i & 15;
    Bsm[l][n] = xdbl[(size_t)(c * CHUNK + l) * NPROJ + RANK + n];
  }
  __syncthreads();
  float a[16], h[16], P[16];
  const float4* al4 = (const float4*)(A_log + (size_t)d * 16);
#pragma unroll
  for (int q = 0; q < 4; q++) {
    float4 v = al4[q];
    a[q * 4 + 0] = -__expf(v.x); a[q * 4 + 1] = -__expf(v.y);
    a[q * 4 + 2] = -__expf(v.z); a[q * 4 + 3] = -__expf(v.w);
  }
#pragma unroll
  for (int n = 0; n < 16; n++) { h[n] = 0.f; P[n] = 1.f; }
  for (int l = 0; l < CHUNK; l++) {
    int gl = c * CHUNK + l;
    float dtv = dt[(size_t)gl * DINNER + d];
    float xv = xconv[(size_t)gl * DINNER + d];
    float dtx = dtv * xv;
#pragma unroll
    for (int n = 0; n < 16; n++) {
      float dA = __expf(dtv * a[n]);
      P[n] *= dA;
      h[n] = dA * h[n] + dtx * Bsm[l][n];
    }
  }
#pragma unroll
  for (int n = 0; n < 16; n++) {
    size_t o = ((size_t)c * 16 + n) * DINNER + d;
    Pout[o] = P[n];
    Hout[o] = h[n];
  }
}

// ============================================================
// Combine: sequential scan over the NCHUNK chunk boundaries.
// ============================================================
__global__ void combine_kernel(const float* __restrict__ P,
                               const float* __restrict__ Hl,
                               float* __restrict__ H0) {
  int i = blockIdx.x * 256 + threadIdx.x;  // n*DINNER + d
  float h = 0.f;
  for (int c = 0; c < NCHUNK; c++) {
    size_t o = (size_t)c * (DINNER * DSTATE) + i;
    H0[o] = h;
    h = P[o] * h + Hl[o];
  }
}

// ============================================================
// Scan phase C: replay with correct h0, fuse y + D*x + silu(z) gate,
// emit yz directly as bf16 for the out-GEMM.
// ============================================================
__global__ __launch_bounds__(256) void scan_c_kernel(
    const float* __restrict__ dt, const float* __restrict__ xconv,
    const float* __restrict__ xdbl, const float* __restrict__ A_log,
    const float* __restrict__ H0, const float* __restrict__ xz,
    const float* __restrict__ Dp, unsigned short* __restrict__ yzbf) {
  __shared__ float Bsm[CHUNK][DSTATE];
  __shared__ float Csm[CHUNK][DSTATE];
  int c = blockIdx.x;
  int d = blockIdx.y * 256 + threadIdx.x;
  for (int i = threadIdx.x; i < CHUNK * DSTATE; i += 256) {
    int l = i >> 4, n = i & 15;
    size_t base = (size_t)(c * CHUNK + l) * NPROJ + RANK;
    Bsm[l][n] = xdbl[base + n];
    Csm[l][n] = xdbl[base + DSTATE + n];
  }
  __syncthreads();
  float a[16], h[16];
  const float4* al4 = (const float4*)(A_log + (size_t)d * 16);
#pragma unroll
  for (int q = 0; q < 4; q++) {
    float4 v = al4[q];
    a[q * 4 + 0] = -__expf(v.x); a[q * 4 + 1] = -__expf(v.y);
    a[q * 4 + 2] = -__expf(v.z); a[q * 4 + 3] = -__expf(v.w);
  }
#pragma unroll
  for (int n = 0; n < 16; n++)
    h[n] = H0[(size_t)c * (DINNER * DSTATE) + n * DINNER + d];
  float dp = Dp[d];
  for (int l = 0; l < CHUNK; l++) {
    int gl = c * CHUNK + l;
    float dtv = dt[(size_t)gl * DINNER + d];
    float xv = xconv[(size_t)gl * DINNER + d];
    float dtx = dtv * xv;
    float y = 0.f;
#pragma unroll
    for (int n = 0; n < 16; n++) {
      float dA = __expf(dtv * a[n]);
      h[n] = dA * h[n] + dtx * Bsm[l][n];
      y += h[n] * Csm[l][n];
    }
    y += xv * dp;
    float zv = xz[(size_t)gl * XZDIM + DINNER + d];
    float sz = zv / (1.0f + __expf(-zv));
    yzbf[(size_t)gl * DINNER + d] = f2bf(y * sz);
  }
}

// ============================================================
extern "C" void kernel_launch(void* const* d_in, const int* in_sizes, int n_in,
                              void* d_out, int out_size, void* d_ws, size_t ws_size,
                              hipStream_t stream) {
  const float* x          = (const float*)d_in[0];
  const float* in_proj_w  = (const float*)d_in[1];
  const float* conv_w     = (const float*)d_in[2];
  const float* conv_b     = (const float*)d_in[3];
  const float* x_proj_w   = (const float*)d_in[4];
  const float* dt_proj_w  = (const float*)d_in[5];
  const float* dt_proj_b  = (const float*)d_in[6];
  const float* A_log      = (const float*)d_in[7];
  const float* D_param    = (const float*)d_in[8];
  const float* out_proj_w = (const float*)d_in[9];
  float* out = (float*)d_out;

  float* ws = (float*)d_ws;
  float* xz    = ws;                                       // 8,388,608 f
  float* xconv = xz    + (size_t)L_SEQ * XZDIM;            // 4,194,304 f
  float* xdbl  = xconv + (size_t)L_SEQ * DINNER;           //   196,608 f
  float* dt    = xdbl  + (size_t)L_SEQ * NPROJ;            // 4,194,304 f
  float* P     = dt    + (size_t)L_SEQ * DINNER;           // 2,097,152 f
  float* Hl    = P     + (size_t)NCHUNK * DINNER * DSTATE; // 2,097,152 f
  float* H0    = Hl    + (size_t)NCHUNK * DINNER * DSTATE; // 2,097,152 f
  float* Cpart = H0    + (size_t)NCHUNK * DINNER * DSTATE; // 2,097,152 f
  unsigned short* bf = (unsigned short*)(Cpart + (size_t)SPLITK * L_SEQ * NPAD);
  unsigned short* x_bf     = bf;                                 // 2,097,152 e
  unsigned short* win_bf   = x_bf     + (size_t)L_SEQ * DMODEL;   // 4,194,304 e
  unsigned short* wout_bf  = win_bf   + (size_t)XZDIM * DMODEL;   // 2,097,152 e
  unsigned short* yz_bf    = wout_bf  + (size_t)DMODEL * DINNER;  // 4,194,304 e
  unsigned short* xconv_bf = yz_bf    + (size_t)L_SEQ * DINNER;   // 4,194,304 e
  unsigned short* wpad_bf  = xconv_bf + (size_t)L_SEQ * DINNER;   //   262,144 e
  unsigned short* dtlr_bf  = wpad_bf  + (size_t)NPAD * DINNER;    //   131,072 e
  unsigned short* dtw_bf   = dtlr_bf  + (size_t)L_SEQ * RANK;     //   131,072 e

  // 0. f32 -> bf16 converts for MFMA operands
  f32_to_bf16_kernel<<<(L_SEQ * DMODEL) / 2048, 256, 0, stream>>>(x, x_bf);
  f32_to_bf16_kernel<<<(XZDIM * DMODEL) / 2048, 256, 0, stream>>>(in_proj_w, win_bf);
  f32_to_bf16_kernel<<<(DMODEL * DINNER) / 2048, 256, 0, stream>>>(out_proj_w, wout_bf);
  f32_to_bf16_kernel<<<(DINNER * RANK) / 2048, 256, 0, stream>>>(dt_proj_w, dtw_bf);
  pad_convert_xw_kernel<<<(NPAD * DINNER) / 2048, 256, 0, stream>>>(x_proj_w, wpad_bf);

  // 1. xz = x @ in_proj_w.T  (2048 x 4096, K=1024)
  //    64x128 tile -> 32x32 = 1024 blocks = 4/CU (occupancy fix)
  gemm_tile<64, 128, 64, 32><<<dim3(XZDIM / 128, L_SEQ / 64), 256, 0, stream>>>(
      x_bf, win_bf, xz, L_SEQ, XZDIM, DMODEL);
  // 2. depthwise conv + SiLU (f32 + bf16)
  conv_silu_kernel<<<(L_SEQ * DINNER) / 256, 256, 0, stream>>>(
      xz, conv_w, conv_b, xconv, xconv_bf);
  // 3. x_dbl = xconv @ x_proj_w.T via split-K MFMA + reduce (emits dtlr bf16)
  gemm_xdbl_splitk<<<dim3(SPLITK, L_SEQ / 128), 256, 0, stream>>>(
      xconv_bf, wpad_bf, Cpart);
  xdbl_reduce_kernel<<<(L_SEQ * NPROJ) / 256, 256, 0, stream>>>(
      Cpart, xdbl, dtlr_bf);
  // 4. dt = softplus(dt_lr @ dt_proj_w.T + b) via MFMA (K=64), fused epilogue
  gemm_dt_bf16<<<dim3(DINNER / 128, L_SEQ / 128), 256, 0, stream>>>(
      dtlr_bf, dtw_bf, dt_proj_b, dt);
  // 5. scan phase A
  scan_a_kernel<<<dim3(NCHUNK, DINNER / 256), 256, 0, stream>>>(
      dt, xconv, xdbl, A_log, P, Hl);
  // 6. combine chunk boundaries
  combine_kernel<<<(DINNER * DSTATE) / 256, 256, 0, stream>>>(P, Hl, H0);
  // 7. scan phase C (replay + gate, bf16 out)
  scan_c_kernel<<<dim3(NCHUNK, DINNER / 256), 256, 0, stream>>>(
      dt, xconv, xdbl, A_log, H0, xz, D_param, yz_bf);
  // 8. out = yz @ out_proj_w.T  (2048 x 1024, K=2048)
  //    64x64 tile -> 16x32 = 512 blocks = 2/CU (was 128 blocks = 0.5/CU)
  gemm_tile<64, 64, 32, 32><<<dim3(DMODEL / 64, L_SEQ / 64), 256, 0, stream>>>(
      yz_bf, wout_bf, out, L_SEQ, DMODEL, DINNER);
}

// Round 15
// 252.955 us; speedup vs baseline: 2.0029x; 1.0706x over previous
//
#include <hip/hip_runtime.h>

// ---- problem constants ----
#define L_SEQ   2048
#define DMODEL  1024
#define DINNER  2048
#define DSTATE  16
#define RANK    64
#define NPROJ   96      // RANK + 2*DSTATE
#define NPAD    128     // padded x_proj rows for MFMA tile
#define XZDIM   4096    // 2*DINNER
#define CHUNK   32
#define NCHUNK  64      // CHUNK*NCHUNK == L_SEQ
#define SPLITK  8       // split-K for the x_dbl GEMM

typedef __bf16 bf16x8 __attribute__((ext_vector_type(8)));
typedef float  f32x4  __attribute__((ext_vector_type(4)));

__device__ __forceinline__ unsigned short f2bf(float f) {
  unsigned int x = __float_as_uint(f);
  x += 0x7FFF + ((x >> 16) & 1);          // round-to-nearest-even
  return (unsigned short)(x >> 16);
}

#define GLD16(g, l)                                                            \
  __builtin_amdgcn_global_load_lds(                                            \
      (const __attribute__((address_space(1))) void*)(g),                      \
      (__attribute__((address_space(3))) void*)(l), 16, 0, 0)

// ============================================================
// f32 -> bf16 convert, 8 elems/thread (n % 2048 == 0)
// ============================================================
__global__ __launch_bounds__(256) void f32_to_bf16_kernel(
    const float* __restrict__ src, unsigned short* __restrict__ dst) {
  size_t i = ((size_t)blockIdx.x * 256 + threadIdx.x) * 8;
  float4 v0 = *(const float4*)(src + i);
  float4 v1 = *(const float4*)(src + i + 4);
  unsigned short o[8];
  o[0] = f2bf(v0.x); o[1] = f2bf(v0.y); o[2] = f2bf(v0.z); o[3] = f2bf(v0.w);
  o[4] = f2bf(v1.x); o[5] = f2bf(v1.y); o[6] = f2bf(v1.z); o[7] = f2bf(v1.w);
  *(ushort4*)(dst + i)     = make_ushort4(o[0], o[1], o[2], o[3]);
  *(ushort4*)(dst + i + 4) = make_ushort4(o[4], o[5], o[6], o[7]);
}

// ============================================================
// x_proj_w (96 x 2048 f32) -> bf16 padded to 128 rows (rows 96+ = 0)
// ============================================================
__global__ __launch_bounds__(256) void pad_convert_xw_kernel(
    const float* __restrict__ src, unsigned short* __restrict__ dst) {
  size_t i = ((size_t)blockIdx.x * 256 + threadIdx.x) * 8;  // over 128*2048
  int row = (int)(i >> 11);
  unsigned short o[8];
  if (row < NPROJ) {
    float4 v0 = *(const float4*)(src + i);
    float4 v1 = *(const float4*)(src + i + 4);
    o[0] = f2bf(v0.x); o[1] = f2bf(v0.y); o[2] = f2bf(v0.z); o[3] = f2bf(v0.w);
    o[4] = f2bf(v1.x); o[5] = f2bf(v1.y); o[6] = f2bf(v1.z); o[7] = f2bf(v1.w);
  } else {
    for (int t = 0; t < 8; t++) o[t] = 0;
  }
  *(ushort4*)(dst + i)     = make_ushort4(o[0], o[1], o[2], o[3]);
  *(ushort4*)(dst + i + 4) = make_ushort4(o[4], o[5], o[6], o[7]);
}

// ============================================================
// Templated bf16 MFMA GEMM:  C[M][N] = A[M][K] * B[N][K]^T
// BMxBN tile, BK=32, 256 thr (4 waves as (BM/WM)x(BN/WN)),
// each wave WMxWN via (WM/16)x(WN/16) frags of 16x16x32.
// ============================================================
template <int BM, int BN, int WM, int WN>
__global__ __launch_bounds__(256) void gemm_tile(
    const unsigned short* __restrict__ A, const unsigned short* __restrict__ B,
    float* __restrict__ C, int M, int N, int K) {
  constexpr int WGN = BN / WN;          // waves along N
  constexpr int FM = WM / 16, FN = WN / 16;
  constexpr int CA = BM * 4 / 256;      // A 16B-chunks per thread
  constexpr int CB = BN * 4 / 256;      // B 16B-chunks per thread
  __shared__ unsigned short As[BM * 32];
  __shared__ unsigned short Bs[BN * 32];
  const int tid  = threadIdx.x;
  const int lane = tid & 63;
  const int wave = tid >> 6;
  const int wr = wave / WGN, wc = wave % WGN;
  const int fr = lane & 15;
  const int kq = (lane >> 4) * 8;
  const size_t bm = blockIdx.y, bn = blockIdx.x;

  f32x4 acc[FM][FN] = {};

  const unsigned short* aptr[CA];
  const unsigned short* bptr[CB];
#pragma unroll
  for (int i = 0; i < CA; i++) {
    int q = tid + i * 256;
    aptr[i] = A + (bm * BM + (q >> 2)) * (size_t)K + (q & 3) * 8;
  }
#pragma unroll
  for (int i = 0; i < CB; i++) {
    int q = tid + i * 256;
    bptr[i] = B + (bn * BN + (q >> 2)) * (size_t)K + (q & 3) * 8;
  }

  for (int k0 = 0; k0 < K; k0 += 32) {
#pragma unroll
    for (int i = 0; i < CA; i++) GLD16(aptr[i] + k0, &As[(tid + i * 256) * 8]);
#pragma unroll
    for (int i = 0; i < CB; i++) GLD16(bptr[i] + k0, &Bs[(tid + i * 256) * 8]);
    __syncthreads();                 // drains vmcnt before LDS reads
    bf16x8 af[FM], bg[FN];
#pragma unroll
    for (int m = 0; m < FM; m++)
      af[m] = *(const bf16x8*)&As[(wr * WM + m * 16 + fr) * 32 + kq];
#pragma unroll
    for (int n = 0; n < FN; n++)
      bg[n] = *(const bf16x8*)&Bs[(wc * WN + n * 16 + fr) * 32 + kq];
#pragma unroll
    for (int m = 0; m < FM; m++)
#pragma unroll
      for (int n = 0; n < FN; n++)
        acc[m][n] = __builtin_amdgcn_mfma_f32_16x16x32_bf16(af[m], bg[n],
                                                            acc[m][n], 0, 0, 0);
    __syncthreads();                 // protect LDS before next stage
  }
  const int cr = (lane >> 4) * 4;    // C/D: col=lane&15, row=(lane>>4)*4+reg
#pragma unroll
  for (int m = 0; m < FM; m++)
#pragma unroll
    for (int n = 0; n < FN; n++) {
      float* cp = C + (bm * BM + wr * WM + m * 16 + cr) * (size_t)N +
                  bn * BN + wc * WN + n * 16 + fr;
#pragma unroll
      for (int r = 0; r < 4; r++) cp[(size_t)r * N] = acc[m][n][r];
    }
}

// ============================================================
// dt GEMM (K=64) + fused bias + softplus, 64x64 tile:
// dt[l][d] = softplus( dtlr[l][:] . dtw[d][:] + dtb[d] )
// 1024 blocks = 4/CU (16 waves/CU) for latency hiding;
// softplus via __expf/__logf intrinsics only (no libm log1pf).
// ============================================================
__global__ __launch_bounds__(256) void gemm_dt64_bf16(
    const unsigned short* __restrict__ A,   // dtlr_bf [L_SEQ][64]
    const unsigned short* __restrict__ B,   // dtw_bf  [DINNER][64]
    const float* __restrict__ bias,         // dtb [DINNER]
    float* __restrict__ dt) {               // [L_SEQ][DINNER]
  __shared__ unsigned short As[64 * 32];
  __shared__ unsigned short Bs[64 * 32];
  const int K = RANK;  // 64
  const int tid  = threadIdx.x;
  const int lane = tid & 63;
  const int wave = tid >> 6;
  const int wr = wave >> 1, wc = wave & 1;   // 2x2 waves of 32x32
  const int fr = lane & 15;
  const int kq = (lane >> 4) * 8;
  const size_t bm = blockIdx.y, bn = blockIdx.x;

  f32x4 acc[2][2] = {};

  const unsigned short* a0 = A + (bm * 64 + (tid >> 2)) * (size_t)K + (tid & 3) * 8;
  const unsigned short* b0 = B + (bn * 64 + (tid >> 2)) * (size_t)K + (tid & 3) * 8;

  for (int k0 = 0; k0 < K; k0 += 32) {
    GLD16(a0 + k0, &As[tid * 8]);
    GLD16(b0 + k0, &Bs[tid * 8]);
    __syncthreads();
    bf16x8 af[2], bg[2];
#pragma unroll
    for (int m = 0; m < 2; m++)
      af[m] = *(const bf16x8*)&As[(wr * 32 + m * 16 + fr) * 32 + kq];
#pragma unroll
    for (int n = 0; n < 2; n++)
      bg[n] = *(const bf16x8*)&Bs[(wc * 32 + n * 16 + fr) * 32 + kq];
#pragma unroll
    for (int m = 0; m < 2; m++)
#pragma unroll
      for (int n = 0; n < 2; n++)
        acc[m][n] = __builtin_amdgcn_mfma_f32_16x16x32_bf16(af[m], bg[n],
                                                            acc[m][n], 0, 0, 0);
    __syncthreads();
  }
  const int cr = (lane >> 4) * 4;
#pragma unroll
  for (int n = 0; n < 2; n++) {
    int col = (int)bn * 64 + wc * 32 + n * 16 + fr;
    float bv = bias[col];
#pragma unroll
    for (int m = 0; m < 2; m++) {
      float* cp = dt + ((size_t)bm * 64 + wr * 32 + m * 16 + cr) * DINNER + col;
#pragma unroll
      for (int r = 0; r < 4; r++) {
        float a = acc[m][n][r] + bv;
        // softplus, fast intrinsics: a>20 -> a  (err < 2e-9)
        float sp = (a > 20.f) ? a : __logf(1.f + __expf(a));
        cp[(size_t)r * DINNER] = sp;
      }
    }
  }
}

// ============================================================
// Split-K GEMM for x_dbl: A = xconv_bf (2048 x 2048), B = wpad_bf
// (128 x 2048). grid (SPLITK, M/128); writes f32 partials.
// ============================================================
__global__ __launch_bounds__(256) void gemm_xdbl_splitk(
    const unsigned short* __restrict__ A, const unsigned short* __restrict__ B,
    float* __restrict__ Cp) {
  __shared__ unsigned short As[128 * 32];
  __shared__ unsigned short Bs[128 * 32];
  const int K = DINNER;
  const int tid  = threadIdx.x;
  const int lane = tid & 63;
  const int wave = tid >> 6;
  const int wr = wave >> 1, wc = wave & 1;
  const int fr = lane & 15;
  const int kq = (lane >> 4) * 8;
  const int s = blockIdx.x;
  const size_t bm = blockIdx.y;

  f32x4 acc[4][4] = {};

  const int q0 = tid, q1 = tid + 256;
  const unsigned short* a0 = A + (bm * 128 + (q0 >> 2)) * (size_t)K + (q0 & 3) * 8;
  const unsigned short* a1 = A + (bm * 128 + (q1 >> 2)) * (size_t)K + (q1 & 3) * 8;
  const unsigned short* b0 = B + ((size_t)(q0 >> 2)) * K + (q0 & 3) * 8;
  const unsigned short* b1 = B + ((size_t)(q1 >> 2)) * K + (q1 & 3) * 8;

  const int kbeg = s * (DINNER / SPLITK), kend = kbeg + DINNER / SPLITK;
  for (int k0 = kbeg; k0 < kend; k0 += 32) {
    GLD16(a0 + k0, &As[q0 * 8]);
    GLD16(a1 + k0, &As[q1 * 8]);
    GLD16(b0 + k0, &Bs[q0 * 8]);
    GLD16(b1 + k0, &Bs[q1 * 8]);
    __syncthreads();
    bf16x8 af[4], bg[4];
#pragma unroll
    for (int m = 0; m < 4; m++)
      af[m] = *(const bf16x8*)&As[(wr * 64 + m * 16 + fr) * 32 + kq];
#pragma unroll
    for (int n = 0; n < 4; n++)
      bg[n] = *(const bf16x8*)&Bs[(wc * 64 + n * 16 + fr) * 32 + kq];
#pragma unroll
    for (int m = 0; m < 4; m++)
#pragma unroll
      for (int n = 0; n < 4; n++)
        acc[m][n] = __builtin_amdgcn_mfma_f32_16x16x32_bf16(af[m], bg[n],
                                                            acc[m][n], 0, 0, 0);
    __syncthreads();
  }
  const int cr = (lane >> 4) * 4;
  float* Cs = Cp + (size_t)s * L_SEQ * NPAD;
#pragma unroll
  for (int m = 0; m < 4; m++)
#pragma unroll
    for (int n = 0; n < 4; n++) {
      float* cp = Cs + (bm * 128 + wr * 64 + m * 16 + cr) * (size_t)NPAD +
                  wc * 64 + n * 16 + fr;
#pragma unroll
      for (int r = 0; r < 4; r++) cp[(size_t)r * NPAD] = acc[m][n][r];
    }
}

// ============================================================
// Reduce split-K partials -> xdbl[l][96] f32 + dtlr_bf[l][64] bf16
// ============================================================
__global__ __launch_bounds__(256) void xdbl_reduce_kernel(
    const float* __restrict__ Cp, float* __restrict__ xdbl,
    unsigned short* __restrict__ dtlr_bf) {
  int i = blockIdx.x * 256 + threadIdx.x;    // 0 .. L_SEQ*NPROJ-1
  int l = i / NPROJ, j = i - l * NPROJ;
  float s = 0.f;
#pragma unroll
  for (int t = 0; t < SPLITK; t++)
    s += Cp[((size_t)t * L_SEQ + l) * NPAD + j];
  xdbl[i] = s;
  if (j < RANK) dtlr_bf[(size_t)l * RANK + j] = f2bf(s);
}

// ============================================================
// Depthwise causal conv (k=4) + bias + SiLU. f32 + bf16 outputs.
// ============================================================
__global__ void conv_silu_kernel(const float* __restrict__ xz,
                                 const float* __restrict__ w,
                                 const float* __restrict__ b,
                                 float* __restrict__ xconv,
                                 unsigned short* __restrict__ xconv_bf) {
  int idx = blockIdx.x * 256 + threadIdx.x;      // l*DINNER + d
  int d = idx & (DINNER - 1);
  int l = idx >> 11;
  float4 wv = *(const float4*)(w + (size_t)d * 4);
  float wa[4] = {wv.x, wv.y, wv.z, wv.w};
  float acc = b[d];
#pragma unroll
  for (int t = 0; t < 4; t++) {
    int ll = l - 3 + t;
    if (ll >= 0) acc += xz[(size_t)ll * XZDIM + d] * wa[t];
  }
  float s = acc / (1.0f + __expf(-acc));
  xconv[idx] = s;
  xconv_bf[idx] = f2bf(s);
}

// ============================================================
// Scan phase A: per (chunk, channel) local scan, h0 = 0.
// ============================================================
__global__ __launch_bounds__(256) void scan_a_kernel(
    const float* __restrict__ dt, const float* __restrict__ xconv,
    const float* __restrict__ xdbl, const float* __restrict__ A_log,
    float* __restrict__ Pout, float* __restrict__ Hout) {
  __shared__ float Bsm[CHUNK][DSTATE];
  int c = blockIdx.x;
  int d = blockIdx.y * 256 + threadIdx.x;
  for (int i = threadIdx.x; i < CHUNK * DSTATE; i += 256) {
    int l = i >> 4, n = i & 15;
    Bsm[l][n] = xdbl[(size_t)(c * CHUNK + l) * NPROJ + RANK + n];
  }
  __syncthreads();
  float a[16], h[16], P[16];
  const float4* al4 = (const float4*)(A_log + (size_t)d * 16);
#pragma unroll
  for (int q = 0; q < 4; q++) {
    float4 v = al4[q];
    a[q * 4 + 0] = -__expf(v.x); a[q * 4 + 1] = -__expf(v.y);
    a[q * 4 + 2] = -__expf(v.z); a[q * 4 + 3] = -__expf(v.w);
  }
#pragma unroll
  for (int n = 0; n < 16; n++) { h[n] = 0.f; P[n] = 1.f; }
  for (int l = 0; l < CHUNK; l++) {
    int gl = c * CHUNK + l;
    float dtv = dt[(size_t)gl * DINNER + d];
    float xv = xconv[(size_t)gl * DINNER + d];
    float dtx = dtv * xv;
#pragma unroll
    for (int n = 0; n < 16; n++) {
      float dA = __expf(dtv * a[n]);
      P[n] *= dA;
      h[n] = dA * h[n] + dtx * Bsm[l][n];
    }
  }
#pragma unroll
  for (int n = 0; n < 16; n++) {
    size_t o = ((size_t)c * 16 + n) * DINNER + d;
    Pout[o] = P[n];
    Hout[o] = h[n];
  }
}

// ============================================================
// Combine: sequential scan over the NCHUNK chunk boundaries.
// ============================================================
__global__ void combine_kernel(const float* __restrict__ P,
                               const float* __restrict__ Hl,
                               float* __restrict__ H0) {
  int i = blockIdx.x * 256 + threadIdx.x;  // n*DINNER + d
  float h = 0.f;
  for (int c = 0; c < NCHUNK; c++) {
    size_t o = (size_t)c * (DINNER * DSTATE) + i;
    H0[o] = h;
    h = P[o] * h + Hl[o];
  }
}

// ============================================================
// Scan phase C: replay with correct h0, fuse y + D*x + silu(z) gate,
// emit yz directly as bf16 for the out-GEMM.
// ============================================================
__global__ __launch_bounds__(256) void scan_c_kernel(
    const float* __restrict__ dt, const float* __restrict__ xconv,
    const float* __restrict__ xdbl, const float* __restrict__ A_log,
    const float* __restrict__ H0, const float* __restrict__ xz,
    const float* __restrict__ Dp, unsigned short* __restrict__ yzbf) {
  __shared__ float Bsm[CHUNK][DSTATE];
  __shared__ float Csm[CHUNK][DSTATE];
  int c = blockIdx.x;
  int d = blockIdx.y * 256 + threadIdx.x;
  for (int i = threadIdx.x; i < CHUNK * DSTATE; i += 256) {
    int l = i >> 4, n = i & 15;
    size_t base = (size_t)(c * CHUNK + l) * NPROJ + RANK;
    Bsm[l][n] = xdbl[base + n];
    Csm[l][n] = xdbl[base + DSTATE + n];
  }
  __syncthreads();
  float a[16], h[16];
  const float4* al4 = (const float4*)(A_log + (size_t)d * 16);
#pragma unroll
  for (int q = 0; q < 4; q++) {
    float4 v = al4[q];
    a[q * 4 + 0] = -__expf(v.x); a[q * 4 + 1] = -__expf(v.y);
    a[q * 4 + 2] = -__expf(v.z); a[q * 4 + 3] = -__expf(v.w);
  }
#pragma unroll
  for (int n = 0; n < 16; n++)
    h[n] = H0[(size_t)c * (DINNER * DSTATE) + n * DINNER + d];
  float dp = Dp[d];
  for (int l = 0; l < CHUNK; l++) {
    int gl = c * CHUNK + l;
    float dtv = dt[(size_t)gl * DINNER + d];
    float xv = xconv[(size_t)gl * DINNER + d];
    float dtx = dtv * xv;
    float y = 0.f;
#pragma unroll
    for (int n = 0; n < 16; n++) {
      float dA = __expf(dtv * a[n]);
      h[n] = dA * h[n] + dtx * Bsm[l][n];
      y += h[n] * Csm[l][n];
    }
    y += xv * dp;
    float zv = xz[(size_t)gl * XZDIM + DINNER + d];
    float sz = zv / (1.0f + __expf(-zv));
    yzbf[(size_t)gl * DINNER + d] = f2bf(y * sz);
  }
}

// ============================================================
extern "C" void kernel_launch(void* const* d_in, const int* in_sizes, int n_in,
                              void* d_out, int out_size, void* d_ws, size_t ws_size,
                              hipStream_t stream) {
  const float* x          = (const float*)d_in[0];
  const float* in_proj_w  = (const float*)d_in[1];
  const float* conv_w     = (const float*)d_in[2];
  const float* conv_b     = (const float*)d_in[3];
  const float* x_proj_w   = (const float*)d_in[4];
  const float* dt_proj_w  = (const float*)d_in[5];
  const float* dt_proj_b  = (const float*)d_in[6];
  const float* A_log      = (const float*)d_in[7];
  const float* D_param    = (const float*)d_in[8];
  const float* out_proj_w = (const float*)d_in[9];
  float* out = (float*)d_out;

  float* ws = (float*)d_ws;
  float* xz    = ws;                                       // 8,388,608 f
  float* xconv = xz    + (size_t)L_SEQ * XZDIM;            // 4,194,304 f
  float* xdbl  = xconv + (size_t)L_SEQ * DINNER;           //   196,608 f
  float* dt    = xdbl  + (size_t)L_SEQ * NPROJ;            // 4,194,304 f
  float* P     = dt    + (size_t)L_SEQ * DINNER;           // 2,097,152 f
  float* Hl    = P     + (size_t)NCHUNK * DINNER * DSTATE; // 2,097,152 f
  float* H0    = Hl    + (size_t)NCHUNK * DINNER * DSTATE; // 2,097,152 f
  float* Cpart = H0    + (size_t)NCHUNK * DINNER * DSTATE; // 2,097,152 f
  unsigned short* bf = (unsigned short*)(Cpart + (size_t)SPLITK * L_SEQ * NPAD);
  unsigned short* x_bf     = bf;                                 // 2,097,152 e
  unsigned short* win_bf   = x_bf     + (size_t)L_SEQ * DMODEL;   // 4,194,304 e
  unsigned short* wout_bf  = win_bf   + (size_t)XZDIM * DMODEL;   // 2,097,152 e
  unsigned short* yz_bf    = wout_bf  + (size_t)DMODEL * DINNER;  // 4,194,304 e
  unsigned short* xconv_bf = yz_bf    + (size_t)L_SEQ * DINNER;   // 4,194,304 e
  unsigned short* wpad_bf  = xconv_bf + (size_t)L_SEQ * DINNER;   //   262,144 e
  unsigned short* dtlr_bf  = wpad_bf  + (size_t)NPAD * DINNER;    //   131,072 e
  unsigned short* dtw_bf   = dtlr_bf  + (size_t)L_SEQ * RANK;     //   131,072 e

  // 0. f32 -> bf16 converts for MFMA operands
  f32_to_bf16_kernel<<<(L_SEQ * DMODEL) / 2048, 256, 0, stream>>>(x, x_bf);
  f32_to_bf16_kernel<<<(XZDIM * DMODEL) / 2048, 256, 0, stream>>>(in_proj_w, win_bf);
  f32_to_bf16_kernel<<<(DMODEL * DINNER) / 2048, 256, 0, stream>>>(out_proj_w, wout_bf);
  f32_to_bf16_kernel<<<(DINNER * RANK) / 2048, 256, 0, stream>>>(dt_proj_w, dtw_bf);
  pad_convert_xw_kernel<<<(NPAD * DINNER) / 2048, 256, 0, stream>>>(x_proj_w, wpad_bf);

  // 1. xz = x @ in_proj_w.T  (2048 x 4096, K=1024)
  //    64x128 tile -> 32x32 = 1024 blocks = 4/CU
  gemm_tile<64, 128, 64, 32><<<dim3(XZDIM / 128, L_SEQ / 64), 256, 0, stream>>>(
      x_bf, win_bf, xz, L_SEQ, XZDIM, DMODEL);
  // 2. depthwise conv + SiLU (f32 + bf16)
  conv_silu_kernel<<<(L_SEQ * DINNER) / 256, 256, 0, stream>>>(
      xz, conv_w, conv_b, xconv, xconv_bf);
  // 3. x_dbl = xconv @ x_proj_w.T via split-K MFMA + reduce (emits dtlr bf16)
  gemm_xdbl_splitk<<<dim3(SPLITK, L_SEQ / 128), 256, 0, stream>>>(
      xconv_bf, wpad_bf, Cpart);
  xdbl_reduce_kernel<<<(L_SEQ * NPROJ) / 256, 256, 0, stream>>>(
      Cpart, xdbl, dtlr_bf);
  // 4. dt = softplus(dt_lr @ dt_proj_w.T + b), 64x64 MFMA tile
  //    -> 32x32 = 1024 blocks = 4/CU (was 256 blocks = 1/CU @ 115us)
  gemm_dt64_bf16<<<dim3(DINNER / 64, L_SEQ / 64), 256, 0, stream>>>(
      dtlr_bf, dtw_bf, dt_proj_b, dt);
  // 5. scan phase A
  scan_a_kernel<<<dim3(NCHUNK, DINNER / 256), 256, 0, stream>>>(
      dt, xconv, xdbl, A_log, P, Hl);
  // 6. combine chunk boundaries
  combine_kernel<<<(DINNER * DSTATE) / 256, 256, 0, stream>>>(P, Hl, H0);
  // 7. scan phase C (replay + gate, bf16 out)
  scan_c_kernel<<<dim3(NCHUNK, DINNER / 256), 256, 0, stream>>>(
      dt, xconv, xdbl, A_log, H0, xz, D_param, yz_bf);
  // 8. out = yz @ out_proj_w.T  (2048 x 1024, K=2048)
  //    64x64 tile -> 16x32 = 512 blocks = 2/CU
  gemm_tile<64, 64, 32, 32><<<dim3(DMODEL / 64, L_SEQ / 64), 256, 0, stream>>>(
      yz_bf, wout_bf, out, L_SEQ, DMODEL, DINNER);
}

// Round 17
// 245.908 us; speedup vs baseline: 2.0603x; 1.0287x over previous
//
#include <hip/hip_runtime.h>

// ---- problem constants ----
#define L_SEQ   2048
#define DMODEL  1024
#define DINNER  2048
#define DSTATE  16
#define RANK    64
#define NPROJ   96      // RANK + 2*DSTATE
#define NPAD    128     // padded x_proj rows for MFMA tile
#define XZDIM   4096    // 2*DINNER
#define CHUNK   32
#define NCHUNK  64      // CHUNK*NCHUNK == L_SEQ
#define SPLITK  16      // split-K for the x_dbl GEMM (256 blocks = 1/CU)

typedef __bf16 bf16x8 __attribute__((ext_vector_type(8)));
typedef float  f32x4  __attribute__((ext_vector_type(4)));

__device__ __forceinline__ unsigned short f2bf(float f) {
  unsigned int x = __float_as_uint(f);
  x += 0x7FFF + ((x >> 16) & 1);          // round-to-nearest-even
  return (unsigned short)(x >> 16);
}

#define GLD16(g, l)                                                            \
  __builtin_amdgcn_global_load_lds(                                            \
      (const __attribute__((address_space(1))) void*)(g),                      \
      (__attribute__((address_space(3))) void*)(l), 16, 0, 0)

// ============================================================
// Merged f32 -> bf16 converts: x (1024 blk), w_in (2048), w_out
// (1024), dtw (64). 2048 elems/block. 4160 blocks total.
// ============================================================
__global__ __launch_bounds__(256) void convert_all_kernel(
    const float* __restrict__ s0, unsigned short* __restrict__ d0,
    const float* __restrict__ s1, unsigned short* __restrict__ d1,
    const float* __restrict__ s2, unsigned short* __restrict__ d2,
    const float* __restrict__ s3, unsigned short* __restrict__ d3) {
  int b = blockIdx.x;
  const float* src; unsigned short* dst; size_t base;
  if (b < 1024)      { src = s0; dst = d0; base = (size_t)b * 2048; }
  else if (b < 3072) { src = s1; dst = d1; base = (size_t)(b - 1024) * 2048; }
  else if (b < 4096) { src = s2; dst = d2; base = (size_t)(b - 3072) * 2048; }
  else               { src = s3; dst = d3; base = (size_t)(b - 4096) * 2048; }
  size_t i = base + (size_t)threadIdx.x * 8;
  float4 v0 = *(const float4*)(src + i);
  float4 v1 = *(const float4*)(src + i + 4);
  unsigned short o[8];
  o[0] = f2bf(v0.x); o[1] = f2bf(v0.y); o[2] = f2bf(v0.z); o[3] = f2bf(v0.w);
  o[4] = f2bf(v1.x); o[5] = f2bf(v1.y); o[6] = f2bf(v1.z); o[7] = f2bf(v1.w);
  *(ushort4*)(dst + i)     = make_ushort4(o[0], o[1], o[2], o[3]);
  *(ushort4*)(dst + i + 4) = make_ushort4(o[4], o[5], o[6], o[7]);
}

// ============================================================
// x_proj_w (96 x 2048 f32) -> bf16 padded to 128 rows (rows 96+ = 0)
// ============================================================
__global__ __launch_bounds__(256) void pad_convert_xw_kernel(
    const float* __restrict__ src, unsigned short* __restrict__ dst) {
  size_t i = ((size_t)blockIdx.x * 256 + threadIdx.x) * 8;  // over 128*2048
  int row = (int)(i >> 11);
  unsigned short o[8];
  if (row < NPROJ) {
    float4 v0 = *(const float4*)(src + i);
    float4 v1 = *(const float4*)(src + i + 4);
    o[0] = f2bf(v0.x); o[1] = f2bf(v0.y); o[2] = f2bf(v0.z); o[3] = f2bf(v0.w);
    o[4] = f2bf(v1.x); o[5] = f2bf(v1.y); o[6] = f2bf(v1.z); o[7] = f2bf(v1.w);
  } else {
    for (int t = 0; t < 8; t++) o[t] = 0;
  }
  *(ushort4*)(dst + i)     = make_ushort4(o[0], o[1], o[2], o[3]);
  *(ushort4*)(dst + i + 4) = make_ushort4(o[4], o[5], o[6], o[7]);
}

// ============================================================
// Templated bf16 MFMA GEMM, 2-PHASE double-buffered staging
// (T3-minimum): stage(t+1) issued BEFORE compute(t); single
// barrier per K-step drains the prefetch + protects LDS reuse.
// C[M][N] = A[M][K] * B[N][K]^T. 256 thr, 4 waves.
// ============================================================
template <int BM, int BN, int WM, int WN>
__global__ __launch_bounds__(256) void gemm_tile(
    const unsigned short* __restrict__ A, const unsigned short* __restrict__ B,
    float* __restrict__ C, int M, int N, int K) {
  constexpr int WGN = BN / WN;          // waves along N
  constexpr int FM = WM / 16, FN = WN / 16;
  constexpr int CA = BM * 4 / 256;      // A 16B-chunks per thread
  constexpr int CB = BN * 4 / 256;      // B 16B-chunks per thread
  __shared__ unsigned short As[2][BM * 32];
  __shared__ unsigned short Bs[2][BN * 32];
  const int tid  = threadIdx.x;
  const int lane = tid & 63;
  const int wave = tid >> 6;
  const int wr = wave / WGN, wc = wave % WGN;
  const int fr = lane & 15;
  const int kq = (lane >> 4) * 8;
  const size_t bm = blockIdx.y, bn = blockIdx.x;

  f32x4 acc[FM][FN] = {};

  const unsigned short* aptr[CA];
  const unsigned short* bptr[CB];
#pragma unroll
  for (int i = 0; i < CA; i++) {
    int q = tid + i * 256;
    aptr[i] = A + (bm * BM + (q >> 2)) * (size_t)K + (q & 3) * 8;
  }
#pragma unroll
  for (int i = 0; i < CB; i++) {
    int q = tid + i * 256;
    bptr[i] = B + (bn * BN + (q >> 2)) * (size_t)K + (q & 3) * 8;
  }

  const int NT = K / 32;
  // prologue: stage tile 0 into buf 0
#pragma unroll
  for (int i = 0; i < CA; i++) GLD16(aptr[i], &As[0][(tid + i * 256) * 8]);
#pragma unroll
  for (int i = 0; i < CB; i++) GLD16(bptr[i], &Bs[0][(tid + i * 256) * 8]);
  __syncthreads();                     // compiler drains vmcnt before barrier

  int cur = 0;
  for (int t = 0; t < NT; t++) {
    if (t + 1 < NT) {                  // prefetch next tile into other buf
      int nk = (t + 1) * 32;
#pragma unroll
      for (int i = 0; i < CA; i++)
        GLD16(aptr[i] + nk, &As[cur ^ 1][(tid + i * 256) * 8]);
#pragma unroll
      for (int i = 0; i < CB; i++)
        GLD16(bptr[i] + nk, &Bs[cur ^ 1][(tid + i * 256) * 8]);
    }
    bf16x8 af[FM], bg[FN];
#pragma unroll
    for (int m = 0; m < FM; m++)
      af[m] = *(const bf16x8*)&As[cur][(wr * WM + m * 16 + fr) * 32 + kq];
#pragma unroll
    for (int n = 0; n < FN; n++)
      bg[n] = *(const bf16x8*)&Bs[cur][(wc * WN + n * 16 + fr) * 32 + kq];
#pragma unroll
    for (int m = 0; m < FM; m++)
#pragma unroll
      for (int n = 0; n < FN; n++)
        acc[m][n] = __builtin_amdgcn_mfma_f32_16x16x32_bf16(af[m], bg[n],
                                                            acc[m][n], 0, 0, 0);
    __syncthreads();   // drains prefetch vmcnt + protects buf[cur] for reuse
    cur ^= 1;
  }
  const int cr = (lane >> 4) * 4;    // C/D: col=lane&15, row=(lane>>4)*4+reg
#pragma unroll
  for (int m = 0; m < FM; m++)
#pragma unroll
    for (int n = 0; n < FN; n++) {
      float* cp = C + (bm * BM + wr * WM + m * 16 + cr) * (size_t)N +
                  bn * BN + wc * WN + n * 16 + fr;
#pragma unroll
      for (int r = 0; r < 4; r++) cp[(size_t)r * N] = acc[m][n][r];
    }
}

// ============================================================
// dt GEMM (K=64) + fused bias + softplus, 64x64 tile (verified).
// ============================================================
__global__ __launch_bounds__(256) void gemm_dt64_bf16(
    const unsigned short* __restrict__ A,   // dtlr_bf [L_SEQ][64]
    const unsigned short* __restrict__ B,   // dtw_bf  [DINNER][64]
    const float* __restrict__ bias,         // dtb [DINNER]
    float* __restrict__ dt) {               // [L_SEQ][DINNER]
  __shared__ unsigned short As[64 * 32];
  __shared__ unsigned short Bs[64 * 32];
  const int K = RANK;  // 64
  const int tid  = threadIdx.x;
  const int lane = tid & 63;
  const int wave = tid >> 6;
  const int wr = wave >> 1, wc = wave & 1;   // 2x2 waves of 32x32
  const int fr = lane & 15;
  const int kq = (lane >> 4) * 8;
  const size_t bm = blockIdx.y, bn = blockIdx.x;

  f32x4 acc[2][2] = {};

  const unsigned short* a0 = A + (bm * 64 + (tid >> 2)) * (size_t)K + (tid & 3) * 8;
  const unsigned short* b0 = B + (bn * 64 + (tid >> 2)) * (size_t)K + (tid & 3) * 8;

  for (int k0 = 0; k0 < K; k0 += 32) {
    GLD16(a0 + k0, &As[tid * 8]);
    GLD16(b0 + k0, &Bs[tid * 8]);
    __syncthreads();
    bf16x8 af[2], bg[2];
#pragma unroll
    for (int m = 0; m < 2; m++)
      af[m] = *(const bf16x8*)&As[(wr * 32 + m * 16 + fr) * 32 + kq];
#pragma unroll
    for (int n = 0; n < 2; n++)
      bg[n] = *(const bf16x8*)&Bs[(wc * 32 + n * 16 + fr) * 32 + kq];
#pragma unroll
    for (int m = 0; m < 2; m++)
#pragma unroll
      for (int n = 0; n < 2; n++)
        acc[m][n] = __builtin_amdgcn_mfma_f32_16x16x32_bf16(af[m], bg[n],
                                                            acc[m][n], 0, 0, 0);
    __syncthreads();
  }
  const int cr = (lane >> 4) * 4;
#pragma unroll
  for (int n = 0; n < 2; n++) {
    int col = (int)bn * 64 + wc * 32 + n * 16 + fr;
    float bv = bias[col];
#pragma unroll
    for (int m = 0; m < 2; m++) {
      float* cp = dt + ((size_t)bm * 64 + wr * 32 + m * 16 + cr) * DINNER + col;
#pragma unroll
      for (int r = 0; r < 4; r++) {
        float a = acc[m][n][r] + bv;
        float sp = (a > 20.f) ? a : __logf(1.f + __expf(a));
        cp[(size_t)r * DINNER] = sp;
      }
    }
  }
}

// ============================================================
// Split-K GEMM for x_dbl: A = xconv_bf (2048 x 2048), B = wpad_bf
// (128 x 2048). grid (SPLITK=16, 16) = 256 blocks; K-range 128.
// ============================================================
__global__ __launch_bounds__(256) void gemm_xdbl_splitk(
    const unsigned short* __restrict__ A, const unsigned short* __restrict__ B,
    float* __restrict__ Cp) {
  __shared__ unsigned short As[128 * 32];
  __shared__ unsigned short Bs[128 * 32];
  const int K = DINNER;
  const int tid  = threadIdx.x;
  const int lane = tid & 63;
  const int wave = tid >> 6;
  const int wr = wave >> 1, wc = wave & 1;
  const int fr = lane & 15;
  const int kq = (lane >> 4) * 8;
  const int s = blockIdx.x;
  const size_t bm = blockIdx.y;

  f32x4 acc[4][4] = {};

  const int q0 = tid, q1 = tid + 256;
  const unsigned short* a0 = A + (bm * 128 + (q0 >> 2)) * (size_t)K + (q0 & 3) * 8;
  const unsigned short* a1 = A + (bm * 128 + (q1 >> 2)) * (size_t)K + (q1 & 3) * 8;
  const unsigned short* b0 = B + ((size_t)(q0 >> 2)) * K + (q0 & 3) * 8;
  const unsigned short* b1 = B + ((size_t)(q1 >> 2)) * K + (q1 & 3) * 8;

  const int kbeg = s * (DINNER / SPLITK), kend = kbeg + DINNER / SPLITK;
  for (int k0 = kbeg; k0 < kend; k0 += 32) {
    GLD16(a0 + k0, &As[q0 * 8]);
    GLD16(a1 + k0, &As[q1 * 8]);
    GLD16(b0 + k0, &Bs[q0 * 8]);
    GLD16(b1 + k0, &Bs[q1 * 8]);
    __syncthreads();
    bf16x8 af[4], bg[4];
#pragma unroll
    for (int m = 0; m < 4; m++)
      af[m] = *(const bf16x8*)&As[(wr * 64 + m * 16 + fr) * 32 + kq];
#pragma unroll
    for (int n = 0; n < 4; n++)
      bg[n] = *(const bf16x8*)&Bs[(wc * 64 + n * 16 + fr) * 32 + kq];
#pragma unroll
    for (int m = 0; m < 4; m++)
#pragma unroll
      for (int n = 0; n < 4; n++)
        acc[m][n] = __builtin_amdgcn_mfma_f32_16x16x32_bf16(af[m], bg[n],
                                                            acc[m][n], 0, 0, 0);
    __syncthreads();
  }
  const int cr = (lane >> 4) * 4;
  float* Cs = Cp + (size_t)s * L_SEQ * NPAD;
#pragma unroll
  for (int m = 0; m < 4; m++)
#pragma unroll
    for (int n = 0; n < 4; n++) {
      float* cp = Cs + (bm * 128 + wr * 64 + m * 16 + cr) * (size_t)NPAD +
                  wc * 64 + n * 16 + fr;
#pragma unroll
      for (int r = 0; r < 4; r++) cp[(size_t)r * NPAD] = acc[m][n][r];
    }
}

// ============================================================
// Reduce split-K partials -> xdbl[l][96] f32 + dtlr_bf[l][64] bf16
// ============================================================
__global__ __launch_bounds__(256) void xdbl_reduce_kernel(
    const float* __restrict__ Cp, float* __restrict__ xdbl,
    unsigned short* __restrict__ dtlr_bf) {
  int i = blockIdx.x * 256 + threadIdx.x;    // 0 .. L_SEQ*NPROJ-1
  int l = i / NPROJ, j = i - l * NPROJ;
  float s = 0.f;
#pragma unroll
  for (int t = 0; t < SPLITK; t++)
    s += Cp[((size_t)t * L_SEQ + l) * NPAD + j];
  xdbl[i] = s;
  if (j < RANK) dtlr_bf[(size_t)l * RANK + j] = f2bf(s);
}

// ============================================================
// Depthwise causal conv (k=4) + bias + SiLU. f32 + bf16 outputs.
// ============================================================
__global__ void conv_silu_kernel(const float* __restrict__ xz,
                                 const float* __restrict__ w,
                                 const float* __restrict__ b,
                                 float* __restrict__ xconv,
                                 unsigned short* __restrict__ xconv_bf) {
  int idx = blockIdx.x * 256 + threadIdx.x;      // l*DINNER + d
  int d = idx & (DINNER - 1);
  int l = idx >> 11;
  float4 wv = *(const float4*)(w + (size_t)d * 4);
  float wa[4] = {wv.x, wv.y, wv.z, wv.w};
  float acc = b[d];
#pragma unroll
  for (int t = 0; t < 4; t++) {
    int ll = l - 3 + t;
    if (ll >= 0) acc += xz[(size_t)ll * XZDIM + d] * wa[t];
  }
  float s = acc / (1.0f + __expf(-acc));
  xconv[idx] = s;
  xconv_bf[idx] = f2bf(s);
}

// ============================================================
// Scan phase A: per (chunk, channel) local scan, h0 = 0.
// ============================================================
__global__ __launch_bounds__(256) void scan_a_kernel(
    const float* __restrict__ dt, const float* __restrict__ xconv,
    const float* __restrict__ xdbl, const float* __restrict__ A_log,
    float* __restrict__ Pout, float* __restrict__ Hout) {
  __shared__ float Bsm[CHUNK][DSTATE];
  int c = blockIdx.x;
  int d = blockIdx.y * 256 + threadIdx.x;
  for (int i = threadIdx.x; i < CHUNK * DSTATE; i += 256) {
    int l = i >> 4, n = i & 15;
    Bsm[l][n] = xdbl[(size_t)(c * CHUNK + l) * NPROJ + RANK + n];
  }
  __syncthreads();
  float a[16], h[16], P[16];
  const float4* al4 = (const float4*)(A_log + (size_t)d * 16);
#pragma unroll
  for (int q = 0; q < 4; q++) {
    float4 v = al4[q];
    a[q * 4 + 0] = -__expf(v.x); a[q * 4 + 1] = -__expf(v.y);
    a[q * 4 + 2] = -__expf(v.z); a[q * 4 + 3] = -__expf(v.w);
  }
#pragma unroll
  for (int n = 0; n < 16; n++) { h[n] = 0.f; P[n] = 1.f; }
  for (int l = 0; l < CHUNK; l++) {
    int gl = c * CHUNK + l;
    float dtv = dt[(size_t)gl * DINNER + d];
    float xv = xconv[(size_t)gl * DINNER + d];
    float dtx = dtv * xv;
#pragma unroll
    for (int n = 0; n < 16; n++) {
      float dA = __expf(dtv * a[n]);
      P[n] *= dA;
      h[n] = dA * h[n] + dtx * Bsm[l][n];
    }
  }
#pragma unroll
  for (int n = 0; n < 16; n++) {
    size_t o = ((size_t)c * 16 + n) * DINNER + d;
    Pout[o] = P[n];
    Hout[o] = h[n];
  }
}

// ============================================================
// Combine: sequential scan over the NCHUNK chunk boundaries.
// ============================================================
__global__ void combine_kernel(const float* __restrict__ P,
                               const float* __restrict__ Hl,
                               float* __restrict__ H0) {
  int i = blockIdx.x * 256 + threadIdx.x;  // n*DINNER + d
  float h = 0.f;
  for (int c = 0; c < NCHUNK; c++) {
    size_t o = (size_t)c * (DINNER * DSTATE) + i;
    H0[o] = h;
    h = P[o] * h + Hl[o];
  }
}

// ============================================================
// Scan phase C: replay with correct h0, fuse y + D*x + silu(z) gate,
// emit yz directly as bf16 for the out-GEMM.
// ============================================================
__global__ __launch_bounds__(256) void scan_c_kernel(
    const float* __restrict__ dt, const float* __restrict__ xconv,
    const float* __restrict__ xdbl, const float* __restrict__ A_log,
    const float* __restrict__ H0, const float* __restrict__ xz,
    const float* __restrict__ Dp, unsigned short* __restrict__ yzbf) {
  __shared__ float Bsm[CHUNK][DSTATE];
  __shared__ float Csm[CHUNK][DSTATE];
  int c = blockIdx.x;
  int d = blockIdx.y * 256 + threadIdx.x;
  for (int i = threadIdx.x; i < CHUNK * DSTATE; i += 256) {
    int l = i >> 4, n = i & 15;
    size_t base = (size_t)(c * CHUNK + l) * NPROJ + RANK;
    Bsm[l][n] = xdbl[base + n];
    Csm[l][n] = xdbl[base + DSTATE + n];
  }
  __syncthreads();
  float a[16], h[16];
  const float4* al4 = (const float4*)(A_log + (size_t)d * 16);
#pragma unroll
  for (int q = 0; q < 4; q++) {
    float4 v = al4[q];
    a[q * 4 + 0] = -__expf(v.x); a[q * 4 + 1] = -__expf(v.y);
    a[q * 4 + 2] = -__expf(v.z); a[q * 4 + 3] = -__expf(v.w);
  }
#pragma unroll
  for (int n = 0; n < 16; n++)
    h[n] = H0[(size_t)c * (DINNER * DSTATE) + n * DINNER + d];
  float dp = Dp[d];
  for (int l = 0; l < CHUNK; l++) {
    int gl = c * CHUNK + l;
    float dtv = dt[(size_t)gl * DINNER + d];
    float xv = xconv[(size_t)gl * DINNER + d];
    float dtx = dtv * xv;
    float y = 0.f;
#pragma unroll
    for (int n = 0; n < 16; n++) {
      float dA = __expf(dtv * a[n]);
      h[n] = dA * h[n] + dtx * Bsm[l][n];
      y += h[n] * Csm[l][n];
    }
    y += xv * dp;
    float zv = xz[(size_t)gl * XZDIM + DINNER + d];
    float sz = zv / (1.0f + __expf(-zv));
    yzbf[(size_t)gl * DINNER + d] = f2bf(y * sz);
  }
}

// ============================================================
extern "C" void kernel_launch(void* const* d_in, const int* in_sizes, int n_in,
                              void* d_out, int out_size, void* d_ws, size_t ws_size,
                              hipStream_t stream) {
  const float* x          = (const float*)d_in[0];
  const float* in_proj_w  = (const float*)d_in[1];
  const float* conv_w     = (const float*)d_in[2];
  const float* conv_b     = (const float*)d_in[3];
  const float* x_proj_w   = (const float*)d_in[4];
  const float* dt_proj_w  = (const float*)d_in[5];
  const float* dt_proj_b  = (const float*)d_in[6];
  const float* A_log      = (const float*)d_in[7];
  const float* D_param    = (const float*)d_in[8];
  const float* out_proj_w = (const float*)d_in[9];
  float* out = (float*)d_out;

  float* ws = (float*)d_ws;
  float* xz    = ws;                                       // 8,388,608 f
  float* xconv = xz    + (size_t)L_SEQ * XZDIM;            // 4,194,304 f
  float* xdbl  = xconv + (size_t)L_SEQ * DINNER;           //   196,608 f
  float* dt    = xdbl  + (size_t)L_SEQ * NPROJ;            // 4,194,304 f
  float* P     = dt    + (size_t)L_SEQ * DINNER;           // 2,097,152 f
  float* Hl    = P     + (size_t)NCHUNK * DINNER * DSTATE; // 2,097,152 f
  float* H0    = Hl    + (size_t)NCHUNK * DINNER * DSTATE; // 2,097,152 f
  float* Cpart = H0    + (size_t)NCHUNK * DINNER * DSTATE; // 4,194,304 f (SPLITK=16)
  unsigned short* bf = (unsigned short*)(Cpart + (size_t)SPLITK * L_SEQ * NPAD);
  unsigned short* x_bf     = bf;                                 // 2,097,152 e
  unsigned short* win_bf   = x_bf     + (size_t)L_SEQ * DMODEL;   // 4,194,304 e
  unsigned short* wout_bf  = win_bf   + (size_t)XZDIM * DMODEL;   // 2,097,152 e
  unsigned short* yz_bf    = wout_bf  + (size_t)DMODEL * DINNER;  // 4,194,304 e
  unsigned short* xconv_bf = yz_bf    + (size_t)L_SEQ * DINNER;   // 4,194,304 e
  unsigned short* wpad_bf  = xconv_bf + (size_t)L_SEQ * DINNER;   //   262,144 e
  unsigned short* dtlr_bf  = wpad_bf  + (size_t)NPAD * DINNER;    //   131,072 e
  unsigned short* dtw_bf   = dtlr_bf  + (size_t)L_SEQ * RANK;     //   131,072 e

  // 0. f32 -> bf16 converts (merged: x, w_in, w_out, dtw) + padded x_proj
  convert_all_kernel<<<4160, 256, 0, stream>>>(
      x, x_bf, in_proj_w, win_bf, out_proj_w, wout_bf, dt_proj_w, dtw_bf);
  pad_convert_xw_kernel<<<(NPAD * DINNER) / 2048, 256, 0, stream>>>(
      x_proj_w, wpad_bf);

  // 1. xz = x @ in_proj_w.T  (2048 x 4096, K=1024), 2-phase staging
  gemm_tile<64, 128, 64, 32><<<dim3(XZDIM / 128, L_SEQ / 64), 256, 0, stream>>>(
      x_bf, win_bf, xz, L_SEQ, XZDIM, DMODEL);
  // 2. depthwise conv + SiLU (f32 + bf16)
  conv_silu_kernel<<<(L_SEQ * DINNER) / 256, 256, 0, stream>>>(
      xz, conv_w, conv_b, xconv, xconv_bf);
  // 3. x_dbl = xconv @ x_proj_w.T via split-K (16) MFMA + reduce
  gemm_xdbl_splitk<<<dim3(SPLITK, L_SEQ / 128), 256, 0, stream>>>(
      xconv_bf, wpad_bf, Cpart);
  xdbl_reduce_kernel<<<(L_SEQ * NPROJ) / 256, 256, 0, stream>>>(
      Cpart, xdbl, dtlr_bf);
  // 4. dt = softplus(dt_lr @ dt_proj_w.T + b), 64x64 MFMA tile
  gemm_dt64_bf16<<<dim3(DINNER / 64, L_SEQ / 64), 256, 0, stream>>>(
      dtlr_bf, dtw_bf, dt_proj_b, dt);
  // 5. scan phase A
  scan_a_kernel<<<dim3(NCHUNK, DINNER / 256), 256, 0, stream>>>(
      dt, xconv, xdbl, A_log, P, Hl);
  // 6. combine chunk boundaries
  combine_kernel<<<(DINNER * DSTATE) / 256, 256, 0, stream>>>(P, Hl, H0);
  // 7. scan phase C (replay + gate, bf16 out)
  scan_c_kernel<<<dim3(NCHUNK, DINNER / 256), 256, 0, stream>>>(
      dt, xconv, xdbl, A_log, H0, xz, D_param, yz_bf);
  // 8. out = yz @ out_proj_w.T  (2048 x 1024, K=2048), 2-phase staging
  gemm_tile<64, 64, 32, 32><<<dim3(DMODEL / 64, L_SEQ / 64), 256, 0, stream>>>(
      yz_bf, wout_bf, out, L_SEQ, DMODEL, DINNER);
}